// Round 6
// baseline (7335.281 us; speedup 1.0000x reference)
//
#include <hip/hip_runtime.h>
#include <stdint.h>

// BetterMCMC R16: 2-barrier pipeline via double-buffered LDS + redundant accept.
//  - s_perm/s_rows/s_pairw double-buffered (112KB LDS). rows flip every step;
//    perm/pairw flip only on accept (no reject copy). Phase-C writes target the
//    alternate buffer -> no writer/reader conflict -> B_mid deleted.
//  - Accept decision computed redundantly by ALL waves (uniform broadcast inputs,
//    deterministic f64/expf -> bit-identical acc). Removes s_accs/s_vn*/s_tmA/s_stm/
//    s_etm round-trips; stm/etm now registers.
//  - All pos-only accept inputs prefetched by all waves in Phase A (hidden).
//  - Leaner per-thread argmax: f32 local (max,first-idx) -> one u64 key -> verified
//    wave_max_u64. Tie semantics unchanged except measure-zero +-0.0 case.
// Race audit (write -> barrier -> read): s_redu A-write/B1/BC-read/B_end; s_lpos same;
// permB/pairwB[alt] C-write/B_end/next-A+BC-read; rowsB[alt] C-write/B_end/next reads.
// Numerics: same formulas/order as R15 (absmax=0 there).

#define NW 4096
#define NSTEPS 2559
#define NTHREADS 1024
#define NWAVES 16

typedef unsigned long long u64;
typedef uint32_t u32;
typedef unsigned short u16;

__device__ __forceinline__ u32 rotl32(u32 v, u32 r) { return (v << r) | (v >> (32u - r)); }

// Threefry-2x32, 20 rounds, exactly as jax/_src/prng.py threefry2x32.
__device__ __forceinline__ void tf2x32(u32 k0, u32 k1, u32 x0, u32 x1, u32* o0, u32* o1) {
  u32 ks2 = k0 ^ k1 ^ 0x1BD11BDAu;
  x0 += k0; x1 += k1;
#define TFR(r0, r1, r2, r3)                      \
  x0 += x1; x1 = rotl32(x1, r0); x1 ^= x0;       \
  x0 += x1; x1 = rotl32(x1, r1); x1 ^= x0;       \
  x0 += x1; x1 = rotl32(x1, r2); x1 ^= x0;       \
  x0 += x1; x1 = rotl32(x1, r3); x1 ^= x0;
  TFR(13, 15, 26, 6)  x0 += k1;  x1 += ks2 + 1u;
  TFR(17, 29, 16, 24) x0 += ks2; x1 += k0 + 2u;
  TFR(13, 15, 26, 6)  x0 += k0;  x1 += k1 + 3u;
  TFR(17, 29, 16, 24) x0 += k1;  x1 += ks2 + 4u;
  TFR(13, 15, 26, 6)  x0 += ks2; x1 += k0 + 5u;
#undef TFR
  *o0 = x0; *o1 = x1;
}

__device__ __forceinline__ float unif01(u32 bits) {
  return __uint_as_float((bits >> 9) | 0x3f800000u) - 1.0f;
}

__device__ __forceinline__ u32 fkey(float f) {
  u32 b = __float_as_uint(f);
  return b ^ ((b >> 31) ? 0xFFFFFFFFu : 0x80000000u);
}

// ---------------- DPP helpers (VALU, no LDS pipe) ----------------
// 0x138 wave_shr1: dest lane n <- lane n-1.  0x130 wave_shl1: dest lane n <- lane n+1.
// bound_ctrl=true -> invalid src = 0.

template <int CTRL>
__device__ __forceinline__ u32 dpp32(u32 v) {
  return (u32)__builtin_amdgcn_update_dpp(0, (int)v, CTRL, 0xF, 0xF, true);
}

template <int CTRL>
__device__ __forceinline__ void dppmax64(u32& hi, u32& lo) {
  u32 h2 = dpp32<CTRL>(hi);
  u32 l2 = dpp32<CTRL>(lo);
  bool g = (h2 > hi) || (h2 == hi && l2 > lo);
  hi = g ? h2 : hi;
  lo = g ? l2 : lo;
}

// wave64 reduce; result valid in lane 63 (zero-fill: key 0 never wins)
__device__ __forceinline__ u64 wave_max_u64(u64 key) {
  u32 lo = (u32)key, hi = (u32)(key >> 32);
  dppmax64<0x111>(hi, lo); dppmax64<0x112>(hi, lo);
  dppmax64<0x114>(hi, lo); dppmax64<0x118>(hi, lo);
  dppmax64<0x142>(hi, lo); dppmax64<0x143>(hi, lo);
  return ((u64)hi << 32) | lo;
}

// 16-lane butterfly -> ALL lanes hold the result
__device__ __forceinline__ u64 bfly16_max_u64(u64 key) {
  u32 lo = (u32)key, hi = (u32)(key >> 32);
  dppmax64<0xB1>(hi, lo); dppmax64<0x4E>(hi, lo);
  dppmax64<0x141>(hi, lo); dppmax64<0x140>(hi, lo);
  return ((u64)hi << 32) | lo;
}

// ---------------- prep kernels (massively parallel) ----------------

#define TT 32
__global__ void transpose_k(const float* __restrict__ in, float* __restrict__ out) {
  __shared__ float tile[TT][TT + 1];
  int x = blockIdx.x * TT + threadIdx.x;
  int y = blockIdx.y * TT + threadIdx.y;
  for (int j = 0; j < TT; j += 8) tile[threadIdx.y + j][threadIdx.x] = in[(u64)(y + j) * NW + x];
  __syncthreads();
  x = blockIdx.y * TT + threadIdx.x;
  y = blockIdx.x * TT + threadIdx.y;
  for (int j = 0; j < TT; j += 8) out[(u64)(y + j) * NW + x] = tile[threadIdx.x][threadIdx.y + j];
}

// Natural layout: gumb[t*NW + i] = gumbel for element i at step t.
__global__ void gumbel_k(float* __restrict__ gumb) {
  long long idx = (long long)blockIdx.x * blockDim.x + threadIdx.x;
  if (idx >= (long long)NSTEPS * NW) return;
  int t = (int)(idx >> 12);
  int i = (int)(idx & (NW - 1));
  u32 kt0, kt1, kc0, kc1, ba, bb;
  tf2x32(0u, 42u, 0u, (u32)t, &kt0, &kt1);
  tf2x32(kt0, kt1, 0u, 1u, &kc0, &kc1);
  tf2x32(kc0, kc1, 0u, (u32)i, &ba, &bb);
  float u = unif01(ba ^ bb);
  if (u == 0.0f) u = 1.17549435e-38f;
  float t1 = (float)log((double)u);
  float t2 = (float)log((double)(-t1));
  gumb[idx] = -t2;
}

__global__ void posu_k(int* __restrict__ posArr, float* __restrict__ uArr) {
  int t = blockIdx.x * blockDim.x + threadIdx.x;
  if (t >= NSTEPS) return;
  u32 kt0, kt1, kp0, kp1, ku0, ku1, k2a, k2b, ra, rb, ua, ub;
  tf2x32(0u, 42u, 0u, (u32)t, &kt0, &kt1);
  tf2x32(kt0, kt1, 0u, 0u, &kp0, &kp1);
  tf2x32(kt0, kt1, 0u, 2u, &ku0, &ku1);
  tf2x32(kp0, kp1, 0u, 1u, &k2a, &k2b);
  tf2x32(k2a, k2b, 0u, 0u, &ra, &rb);
  posArr[t] = (int)((ra ^ rb) & (u32)(NW - 1));
  tf2x32(ku0, ku1, 0u, 0u, &ua, &ub);
  uArr[t] = unif01(ua ^ ub);
}

// ---------------- main chain kernel ----------------

__global__ __launch_bounds__(NTHREADS)
void mcmc_fast14(const float* __restrict__ bigram,
                 const float* __restrict__ bigT,
                 const float* __restrict__ gumb,
                 const int* __restrict__ posArr,
                 const float* __restrict__ uArr,
                 const float* __restrict__ startv,
                 const float* __restrict__ endv,
                 int* __restrict__ out) {
  __shared__ u16    s_permB[2][NW];    // 16 KB
  __shared__ float2 s_rowsB[2][NW];    // 64 KB  (T[w], B[w]) for current tm
  __shared__ float  s_pairwB[2][NW];   // 32 KB
  __shared__ u64    s_redu[NWAVES];
  __shared__ float  s_lpos;

  const int tid = threadIdx.x;
  const int lane = tid & 63;
  const int wid = tid >> 6;
  const int j0 = tid * 4;             // first owned element

  int pc = 0, rc = 0, qc = 0;         // current buffer selectors (uniform)

  // ---- init into buffer 0 ----
  for (int i = tid; i < NW; i += NTHREADS) s_permB[0][i] = (u16)i;
  ushort4 pq = make_ushort4((u16)j0, (u16)(j0 + 1), (u16)(j0 + 2), (u16)(j0 + 3));
  float4 pwq;
  pwq.x = bigram[(u64)j0 * NW + (j0 + 1)];
  pwq.y = bigram[(u64)(j0 + 1) * NW + (j0 + 2)];
  pwq.z = bigram[(u64)(j0 + 2) * NW + (j0 + 3)];
  pwq.w = (j0 + 3 < NW - 1) ? bigram[(u64)(j0 + 3) * NW + (j0 + 4)] : 0.0f;
  ((float4*)s_pairwB[0])[tid] = pwq;

  int pos = posArr[0];
  int pn1 = posArr[1];
  float u_cur = uArr[0];
  float un1 = uArr[1];
  int tm = pos;                        // identity perm: perm[pos] == pos
  {
    float4 rb4 = ((const float4*)(bigram + (u64)tm * NW))[tid];
    float4 rt4 = ((const float4*)(bigT + (u64)tm * NW))[tid];
    ((float4*)(&s_rowsB[0][j0]))[0] = make_float4(rt4.x, rb4.x, rt4.y, rb4.y);
    ((float4*)(&s_rowsB[0][j0]))[1] = make_float4(rt4.z, rb4.z, rt4.w, rb4.w);
  }
  // uniform per-thread chain state (all threads carry identical values)
  float stm_cur = startv[tm];
  float etm_cur = endv[tm];
  float start_cur = startv[0];
  float end_cur = endv[NW - 1];

  float4 g4 = ((const float4*)gumb)[tid];
  __syncthreads();

  for (int t = 0; t < NSTEPS; ++t) {
    const u16*    permC  = s_permB[pc];
    const float2* rowsC  = s_rowsB[rc];
    const float*  pairwC = s_pairwB[qc];

    // ---- Phase A ----
    const float gg[4] = {g4.x, g4.y, g4.z, g4.w};
    // stream prefetch first (max cover before B1's vmcnt drain)
    int pn2; float un2;
    {
      int tn = (t + 1 < NSTEPS) ? (t + 1) : (NSTEPS - 1);
      int tn2 = (t + 2 < NSTEPS) ? (t + 2) : (NSTEPS - 1);
      g4 = ((const float4*)(gumb + ((u64)tn << 12)))[tid];   // for step t+1
      pn2 = posArr[tn2];
      un2 = uArr[tn2];
    }
    // speculative reject-branch staging (tmR known pre-argmax)
    const int tmR = (int)permC[pn1];
    const float4 rbR = ((const float4*)(bigram + (u64)tmR * NW))[tid];
    const float4 rtR = ((const float4*)(bigT + (u64)tmR * NW))[tid];
    const float stmR = startv[tmR];
    const float etmR = endv[tmR];
    // all-wave uniform prefetch of pos-only accept inputs (broadcast reads)
    const int pl = (pos > 0) ? (int)permC[pos - 1] : 0;
    const int pr = (pos < NW - 1) ? (int)permC[pos + 1] : 0;
    const float remL = (pos > 0) ? rowsC[pl].x : 0.0f;       // B[P[pos-1], tm]
    const float remR = (pos < NW - 1) ? rowsC[pr].y : 0.0f;  // B[tm, P[pos+1]]
    const float brgv = (pos > 0 && pos < NW - 1) ? bigram[(u64)pl * NW + pr] : 0.0f;
    const float sv0m = startv[(int)permC[(0 >= pos) ? 1 : 0]];
    const float ev1m = endv[(int)permC[(NW - 2) + ((NW - 2) >= pos)]];

    // perm block (registers) + cross-wave edges
    const int p0i = pq.x, p1i = pq.y, p2i = pq.z, p3i = pq.w;
    int pm1, pp4;
    {
      u32 lo = (u32)pq.x | ((u32)pq.y << 16);
      u32 hi = (u32)pq.z | ((u32)pq.w << 16);
      pm1 = (int)(dpp32<0x138>(hi) >> 16);                   // lane-1's p3 = perm[j0-1]
      pp4 = (int)(dpp32<0x130>(lo) & 0xFFFFu);               // lane+1's p0 = perm[j0+4]
      if (lane == 0)  pm1 = (tid > 0) ? (int)permC[j0 - 1] : 0;
      if (lane == 63) pp4 = (tid < NTHREADS - 1) ? (int)permC[j0 + 4] : 0;
    }
    // pairw cross-wave edge reads (consumed lazily on accept)
    float pwm1_e = 0.0f, pwp4_e = 0.0f;
    if (lane == 0 && tid > 0) pwm1_e = pairwC[j0 - 1];
    if (lane == 63 && tid < NTHREADS - 1) pwp4_e = pairwC[j0 + 4];

    // perm2 values for owned j (register selects)
    const int w0 = (j0     >= pos) ? p1i : p0i;
    const int w1 = (j0 + 1 >= pos) ? p2i : p1i;
    const int w2 = (j0 + 2 >= pos) ? p3i : p2i;
    const int w3 = (j0 + 3 >= pos) ? pp4 : p3i;
    const int wprev = ((j0 - 1) >= pos) ? p0i : pm1;         // perm2[j0-1]
    // interleaved gathers: f_k = (T[w_k], B[w_k])
    const float2 f0 = rowsC[w0];
    const float2 f1 = rowsC[w1];
    const float2 f2 = rowsC[w2];
    const float2 f3 = rowsC[w3];
    float tprev = __uint_as_float(dpp32<0x138>(__float_as_uint(f3.x)));
    if (lane == 0 && tid > 0) tprev = rowsC[wprev].x;
    // logits (bit-identical adds: T + B)
    float li0 = tprev + f0.y;
    float li1 = f0.x + f1.y;
    float li2 = f1.x + f2.y;
    float li3 = f2.x + f3.y;
    if (tid == 0)            li0 = stm_cur + f0.y;
    if (tid == NTHREADS - 1) li3 = etm_cur + f2.x;
    if ((pos >> 2) == tid) {
      int k = pos & 3;
      s_lpos = (k == 0) ? li0 : ((k == 1) ? li1 : ((k == 2) ? li2 : li3));
    }
    // local argmax (first index wins ties) -> single u64 key -> wave reduce
    {
      float sv0_ = gg[0] + li0;
      float sv1_ = gg[1] + li1;
      float sv2_ = gg[2] + li2;
      float sv3_ = gg[3] + li3;
      float mx = sv0_; int ix = j0;
      if (sv1_ > mx) { mx = sv1_; ix = j0 + 1; }
      if (sv2_ > mx) { mx = sv2_; ix = j0 + 2; }
      if (sv3_ > mx) { mx = sv3_; ix = j0 + 3; }
      u64 key = ((u64)fkey(mx) << 32) | (u32)(NW - 1 - ix);
      key = wave_max_u64(key);
      if (lane == 63) s_redu[wid] = key;
    }
    __syncthreads();                                                  // B1

    // ---- Phase B+C: redundant decision on ALL waves; commit to alt buffers ----
    u64 bb = bfly16_max_u64(s_redu[lane & 15]);
    const int np = NW - 1 - (int)(bb & 0xFFFFFFFFu);
    const int ls_i = (np >= 1) ? ((np - 1) + ((np - 1) >= pos)) : 0;
    const int rs_i = (np <= NW - 2) ? (np + (np >= pos)) : 0;
    const int l_s = (int)permC[ls_i];
    const int r_s = (int)permC[rs_i];
    const int tmA = (pn1 < np) ? (int)permC[pn1 + (pn1 >= pos)]
                  : ((pn1 == np) ? tm : (int)permC[(pn1 - 1) + ((pn1 - 1) >= pos)]);
    float splitv = 0.0f;
    if (np > 0 && np < NW - 1) {
      int k_s = (np - 1) + ((np - 1) >= pos);
      splitv = (np == pos) ? brgv : pairwC[k_s];
    }
    const float vnpm1 = (np >= 1)      ? rowsC[l_s].x : 0.0f;
    const float vnp   = (np <= NW - 2) ? rowsC[r_s].y : 0.0f;
    const float sv0 = (np > 0) ? sv0m : stm_cur;
    const float ev1 = (np < NW - 1) ? ev1m : etm_cur;
    const float lposv = s_lpos;
    double delta = 0.0;
    if (pos > 0)                 delta -= (double)remL;
    if (pos < NW - 1)            delta -= (double)remR;
    if (pos > 0 && pos < NW - 1) delta += (double)brgv;
    if (np > 0)                  delta += (double)vnpm1;
    if (np < NW - 1)             delta += (double)vnp;
    if (np > 0 && np < NW - 1)   delta -= (double)splitv;
    delta += ((double)sv0 - (double)start_cur) + ((double)ev1 - (double)end_cur);
    const float lnp = (np == 0) ? (stm_cur + vnp)
                    : ((np == NW - 1) ? (etm_cur + vnpm1) : (vnpm1 + vnp));
    const double ed = delta + ((double)lnp - (double)lposv);
    const float a = fminf(1.0f, expf((float)ed));
    const int acc = (a > u_cur) ? 1 : 0;      // bit-identical on every thread
    if (acc) { start_cur = sv0; end_cur = ev1; }

    // commit (lazy: accept only)
    int tm_next;
    float4 rb, rt;
    float stmN, etmN;
    ushort4 st = pq;
    float4 npw = pwq;
    if (acc) {
      tm_next = tmA;
      rb = ((const float4*)(bigram + (u64)tm_next * NW))[tid];   // issue early
      rt = ((const float4*)(bigT + (u64)tm_next * NW))[tid];
      stmN = startv[tm_next];
      etmN = endv[tm_next];
      // register stash -> alternate perm buffer
      st.x = (j0     < np) ? (u16)w0 : ((j0     == np) ? (u16)tm : (u16)wprev);
      st.y = (j0 + 1 < np) ? (u16)w1 : ((j0 + 1 == np) ? (u16)tm : (u16)w0);
      st.z = (j0 + 2 < np) ? (u16)w2 : ((j0 + 2 == np) ? (u16)tm : (u16)w1);
      st.w = (j0 + 3 < np) ? (u16)w3 : ((j0 + 3 == np) ? (u16)tm : (u16)w2);
      ((ushort4*)s_permB[pc ^ 1])[tid] = st;
      // pairw maintenance -> alternate pairw buffer
      float pwm1 = __uint_as_float(dpp32<0x138>(__float_as_uint(pwq.w)));
      float pwp4 = __uint_as_float(dpp32<0x130>(__float_as_uint(pwq.x)));
      if (lane == 0)  pwm1 = pwm1_e;
      if (lane == 63) pwp4 = pwp4_e;
      float nv0, nv1, nv2, nv3;
      {
        float vA0 = (j0     < pos - 1) ? pwq.x : pwq.y;
        float vB0 = (j0 - 1 < pos - 1) ? pwm1  : pwq.x;
        nv0 = (j0 < np) ? vA0 : vB0;
        int kk0 = (j0 < np) ? j0 : j0 - 1;
        if (kk0 == pos - 1) nv0 = brgv;

        float vA1 = (j0 + 1 < pos - 1) ? pwq.y : pwq.z;
        float vB1 = (j0     < pos - 1) ? pwq.x : pwq.y;
        nv1 = (j0 + 1 < np) ? vA1 : vB1;
        int kk1 = (j0 + 1 < np) ? j0 + 1 : j0;
        if (kk1 == pos - 1) nv1 = brgv;

        float vA2 = (j0 + 2 < pos - 1) ? pwq.z : pwq.w;
        float vB2 = (j0 + 1 < pos - 1) ? pwq.y : pwq.z;
        nv2 = (j0 + 2 < np) ? vA2 : vB2;
        int kk2 = (j0 + 2 < np) ? j0 + 2 : j0 + 1;
        if (kk2 == pos - 1) nv2 = brgv;

        float vA3 = (j0 + 3 < pos - 1) ? pwq.w : pwp4;
        float vB3 = (j0 + 2 < pos - 1) ? pwq.z : pwq.w;
        nv3 = (j0 + 3 < np) ? vA3 : vB3;
        int kk3 = (j0 + 3 < np) ? j0 + 3 : j0 + 2;
        if (kk3 == pos - 1) nv3 = brgv;
      }
      float o0 = (j0     == np - 1) ? vnpm1 : ((j0     == np) ? vnp : nv0);
      float o1 = (j0 + 1 == np - 1) ? vnpm1 : ((j0 + 1 == np) ? vnp : nv1);
      float o2 = (j0 + 2 == np - 1) ? vnpm1 : ((j0 + 2 == np) ? vnp : nv2);
      float o3 = (j0 + 3 == np - 1) ? vnpm1 : ((j0 + 3 == np) ? vnp : nv3);
      if (j0 + 3 >= NW - 1) o3 = 0.0f;                       // pairw[NW-1] stays 0
      npw = make_float4(o0, o1, o2, o3);
      ((float4*)s_pairwB[qc ^ 1])[tid] = npw;
      pc ^= 1; qc ^= 1;
    } else {
      tm_next = tmR;
      rb = rbR; rt = rtR;
      stmN = stmR; etmN = etmR;
    }
    // rows -> alternate buffer (every step)
    ((float4*)(&s_rowsB[rc ^ 1][j0]))[0] = make_float4(rt.x, rb.x, rt.y, rb.y);
    ((float4*)(&s_rowsB[rc ^ 1][j0]))[1] = make_float4(rt.z, rb.z, rt.w, rb.w);
    rc ^= 1;
    pq = st; pwq = npw;
    stm_cur = stmN; etm_cur = etmN;
    tm = tm_next;
    pos = pn1; u_cur = un1;
    pn1 = pn2; un1 = un2;

    // ---- emit thinned sample (registers -> global) ----
    if ((t % 10) == 8) {
      int row = (t - 8) / 10;
      int4 o4;
      o4.x = (int)pq.x; o4.y = (int)pq.y; o4.z = (int)pq.z; o4.w = (int)pq.w;
      ((int4*)(out + (u64)row * NW))[tid] = o4;
    }
    __syncthreads();                                                  // B_end
  }
}

// ---------------- fallback (R2 kernel, verified) ----------------

__global__ __launch_bounds__(NTHREADS)
void mcmc_kernel(const float* __restrict__ bigram,
                 const float* __restrict__ startv,
                 const float* __restrict__ endv,
                 int* __restrict__ out) {
  __shared__ int    s_perm[NW];
  __shared__ float  s_logit[NW];
  __shared__ float  s_gath[NW];
  __shared__ float  s_redf[NWAVES];
  __shared__ u64    s_redu[NWAVES];
  __shared__ double s_redd[NWAVES];
  __shared__ float  s_m, s_Z, s_w;
  __shared__ int    s_pos, s_tm, s_np, s_acc;
  __shared__ u32    s_kcat0, s_kcat1, s_ku0, s_ku1;

  const int tid = threadIdx.x;
  const int lane = tid & 63;
  const int wid = tid >> 6;

  for (int i = tid; i < NW; i += NTHREADS) s_perm[i] = i;
  for (int j = tid; j < NW - 1; j += NTHREADS) s_gath[j] = bigram[(u64)j * NW + (j + 1)];
  __syncthreads();
  if (tid == 0) {
    float S = 0.0f;
    for (int j = 0; j < NW - 1; ++j) S += s_gath[j];
    S = S + startv[0];
    S = S + endv[NW - 1];
    s_w = S;
  }
  __syncthreads();

  for (int t = 0; t < NSTEPS; ++t) {
    if (tid == 0) {
      u32 kt0, kt1;
      tf2x32(0u, 42u, 0u, (u32)t, &kt0, &kt1);
      u32 kp0, kp1, kc0, kc1, ku0, ku1;
      tf2x32(kt0, kt1, 0u, 0u, &kp0, &kp1);
      tf2x32(kt0, kt1, 0u, 1u, &kc0, &kc1);
      tf2x32(kt0, kt1, 0u, 2u, &ku0, &ku1);
      u32 k2a, k2b, ra, rb;
      tf2x32(kp0, kp1, 0u, 1u, &k2a, &k2b);
      tf2x32(k2a, k2b, 0u, 0u, &ra, &rb);
      int pos = (int)((ra ^ rb) & (u32)(NW - 1));
      s_pos = pos;
      s_tm = s_perm[pos];
      s_kcat0 = kc0; s_kcat1 = kc1; s_ku0 = ku0; s_ku1 = ku1;
    }
    __syncthreads();
    const int pos = s_pos, tm = s_tm;

    float lmax = -3.402823466e+38f;
    for (int i = tid; i < NW; i += NTHREADS) {
      float li;
      if (i == 0) {
        int r = s_perm[(0 >= pos) ? 1 : 0];
        li = startv[tm] + bigram[(u64)tm * NW + r];
      } else if (i == NW - 1) {
        int l = s_perm[((NW - 2) >= pos) ? (NW - 1) : (NW - 2)];
        li = endv[tm] + bigram[(u64)l * NW + tm];
      } else {
        int l = s_perm[((i - 1) >= pos) ? i : (i - 1)];
        int r = s_perm[(i >= pos) ? (i + 1) : i];
        li = bigram[(u64)l * NW + tm] + bigram[(u64)tm * NW + r];
      }
      s_logit[i] = li;
      lmax = fmaxf(lmax, li);
    }
    for (int o = 32; o > 0; o >>= 1) lmax = fmaxf(lmax, __shfl_down(lmax, o, 64));
    if (lane == 0) s_redf[wid] = lmax;
    __syncthreads();
    if (tid == 0) {
      float m = s_redf[0];
      for (int w = 1; w < NWAVES; ++w) m = fmaxf(m, s_redf[w]);
      s_m = m;
    }
    __syncthreads();
    const float m = s_m;

    double zacc = 0.0;
    u64 best = 0;
    const u32 kc0 = s_kcat0, kc1 = s_kcat1;
    for (int i = tid; i < NW; i += NTHREADS) {
      float li = s_logit[i];
      float ex = (float)exp((double)(li - m));
      zacc += (double)ex;
      u32 ba, bb;
      tf2x32(kc0, kc1, 0u, (u32)i, &ba, &bb);
      float u = unif01(ba ^ bb);
      if (u == 0.0f) u = 1.17549435e-38f;
      float t1 = (float)log((double)u);
      float t2 = (float)log((double)(-t1));
      float g = -t2;
      float sv = g + li;
      u64 key = ((u64)fkey(sv) << 32) | (u32)(NW - 1 - i);
      if (key > best) best = key;
    }
    for (int o = 32; o > 0; o >>= 1) {
      u64 w = __shfl_down(best, o, 64);
      if (w > best) best = w;
      zacc += __shfl_down(zacc, o, 64);
    }
    if (lane == 0) { s_redu[wid] = best; s_redd[wid] = zacc; }
    __syncthreads();
    if (tid == 0) {
      u64 b = s_redu[0]; double z = s_redd[0];
      for (int w = 1; w < NWAVES; ++w) {
        if (s_redu[w] > b) b = s_redu[w];
        z += s_redd[w];
      }
      s_np = NW - 1 - (int)(b & 0xFFFFFFFFu);
      s_Z = (float)z;
    }
    __syncthreads();
    const int np = s_np;

    for (int j = tid; j < NW - 1; j += NTHREADS) {
      int a = (j < np) ? s_perm[j + (j >= pos)]
                       : ((j == np) ? tm : s_perm[(j - 1) + ((j - 1) >= pos)]);
      int j1 = j + 1;
      int b = (j1 < np) ? s_perm[j1 + (j1 >= pos)]
                        : ((j1 == np) ? tm : s_perm[(j1 - 1) + ((j1 - 1) >= pos)]);
      s_gath[j] = bigram[(u64)a * NW + b];
    }
    __syncthreads();

    if (tid == 0) {
      float S = 0.0f;
      for (int j = 0; j < NW - 1; ++j) S += s_gath[j];
      int s0 = (0 < np) ? s_perm[(0 >= pos) ? 1 : 0] : tm;
      int sl = ((NW - 1) == np) ? tm : s_perm[(NW - 2) + ((NW - 2) >= pos)];
      S = S + startv[s0];
      S = S + endv[sl];
      float dw = S - s_w;
      float e1 = (float)exp((double)dw);
      float en = (float)exp((double)(s_logit[np] - m));
      float eo = (float)exp((double)(s_logit[pos] - m));
      float pn = en / s_Z;
      float po = eo / s_Z;
      float acc = e1 * pn;
      acc = acc / po;
      acc = fminf(1.0f, acc);
      u32 ua, ub;
      tf2x32(s_ku0, s_ku1, 0u, 0u, &ua, &ub);
      float u = unif01(ua ^ ub);
      int accept = (acc > u) ? 1 : 0;
      s_acc = accept;
      if (accept) s_w = S;
    }
    __syncthreads();

    int stash[4];
    if (s_acc) {
      for (int k = 0; k < 4; ++k) {
        int i = tid + k * NTHREADS;
        stash[k] = (i < np) ? s_perm[i + (i >= pos)]
                            : ((i == np) ? tm : s_perm[(i - 1) + ((i - 1) >= pos)]);
      }
    }
    __syncthreads();
    if (s_acc) {
      for (int k = 0; k < 4; ++k) {
        int i = tid + k * NTHREADS;
        s_perm[i] = stash[k];
      }
    }
    __syncthreads();

    if (((t + 1) % 10) == 9) {
      int row = (t - 8) / 10;
      for (int i = tid; i < NW; i += NTHREADS) out[(u64)row * NW + i] = s_perm[i];
    }
    __syncthreads();
  }
}

extern "C" void kernel_launch(void* const* d_in, const int* in_sizes, int n_in,
                              void* d_out, int out_size, void* d_ws, size_t ws_size,
                              hipStream_t stream) {
  const float* bigram = (const float*)d_in[1];
  const float* startv = (const float*)d_in[2];
  const float* endv   = (const float*)d_in[3];
  int* out = (int*)d_out;

  const size_t needT = (size_t)NW * NW * sizeof(float);        // 64 MB
  const size_t needG = (size_t)NSTEPS * NW * sizeof(float);    // ~41.9 MB
  const size_t needP = (size_t)NSTEPS * (sizeof(int) + sizeof(float));

  if (ws_size >= needT + needG + needP) {
    float* bigT = (float*)d_ws;
    float* gumb = (float*)((char*)d_ws + needT);
    int* posArr = (int*)((char*)d_ws + needT + needG);
    float* uArr = (float*)((char*)d_ws + needT + needG + (size_t)NSTEPS * sizeof(int));
    hipLaunchKernelGGL(transpose_k, dim3(NW / TT, NW / TT), dim3(TT, 8), 0, stream,
                       bigram, bigT);
    long long ng = (long long)NSTEPS * NW;
    hipLaunchKernelGGL(gumbel_k, dim3((unsigned)((ng + 255) / 256)), dim3(256), 0, stream,
                       gumb);
    hipLaunchKernelGGL(posu_k, dim3((NSTEPS + 255) / 256), dim3(256), 0, stream,
                       posArr, uArr);
    hipLaunchKernelGGL(mcmc_fast14, dim3(1), dim3(NTHREADS), 0, stream,
                       bigram, bigT, gumb, posArr, uArr, startv, endv, out);
  } else {
    hipLaunchKernelGGL(mcmc_kernel, dim3(1), dim3(NTHREADS), 0, stream,
                       bigram, startv, endv, out);
  }
}

// Round 7
// 6496.118 us; speedup vs baseline: 1.1292x; 1.1292x over previous
//
#include <hip/hip_runtime.h>
#include <stdint.h>

// BetterMCMC R17: R15 base (best: 6400us) + three surgical, numerics-preserving cuts.
//  1. LIGHT BARRIERS: s_waitcnt lgkmcnt(0) + raw s_barrier (inline asm). LDS ordering
//     kept (all cross-phase deps are LDS, audited); speculative global loads (gumbel,
//     tmR rows) stay in flight across barriers instead of draining at each one.
//  2. f32/u32 argmax: local f32 first-wins max -> fkey -> 6x DPP v_max_u32 ->
//     readlane(63) -> ballot/ffs -> lowest tied lane writes u64 key. Lane order =
//     index order (contiguous mapping) => tie semantics EXACTLY match the u64 reduce.
//     ~48 -> ~14 instrs/wave.
//  3. Split s_rowT/s_rowB (R12 layout), b32 random gathers (~2-way bank aliasing,
//     free per m136) instead of b64 (~4-way). Same values, same add order.
// R16 lesson applied: decision stays wave0-only (serial LDS chains must not be
// replicated across waves); B_mid stays.

#define NW 4096
#define NSTEPS 2559
#define NTHREADS 1024
#define NWAVES 16

typedef unsigned long long u64;
typedef uint32_t u32;
typedef unsigned short u16;

__device__ __forceinline__ u32 rotl32(u32 v, u32 r) { return (v << r) | (v >> (32u - r)); }

// Threefry-2x32, 20 rounds, exactly as jax/_src/prng.py threefry2x32.
__device__ __forceinline__ void tf2x32(u32 k0, u32 k1, u32 x0, u32 x1, u32* o0, u32* o1) {
  u32 ks2 = k0 ^ k1 ^ 0x1BD11BDAu;
  x0 += k0; x1 += k1;
#define TFR(r0, r1, r2, r3)                      \
  x0 += x1; x1 = rotl32(x1, r0); x1 ^= x0;       \
  x0 += x1; x1 = rotl32(x1, r1); x1 ^= x0;       \
  x0 += x1; x1 = rotl32(x1, r2); x1 ^= x0;       \
  x0 += x1; x1 = rotl32(x1, r3); x1 ^= x0;
  TFR(13, 15, 26, 6)  x0 += k1;  x1 += ks2 + 1u;
  TFR(17, 29, 16, 24) x0 += ks2; x1 += k0 + 2u;
  TFR(13, 15, 26, 6)  x0 += k0;  x1 += k1 + 3u;
  TFR(17, 29, 16, 24) x0 += k1;  x1 += ks2 + 4u;
  TFR(13, 15, 26, 6)  x0 += ks2; x1 += k0 + 5u;
#undef TFR
  *o0 = x0; *o1 = x1;
}

__device__ __forceinline__ float unif01(u32 bits) {
  return __uint_as_float((bits >> 9) | 0x3f800000u) - 1.0f;
}

__device__ __forceinline__ u32 fkey(float f) {
  u32 b = __float_as_uint(f);
  return b ^ ((b >> 31) ? 0xFFFFFFFFu : 0x80000000u);
}

// Light barrier: LDS-ordering only; global loads stay in flight (no vmcnt drain).
__device__ __forceinline__ void light_bar() {
  asm volatile("s_waitcnt lgkmcnt(0)" ::: "memory");
  __builtin_amdgcn_s_barrier();
  __builtin_amdgcn_sched_barrier(0);
  asm volatile("" ::: "memory");
}

// ---------------- DPP helpers (VALU, no LDS pipe) ----------------
// 0x138 wave_shr1: dest lane n <- lane n-1.  0x130 wave_shl1: dest lane n <- lane n+1.
// bound_ctrl=true -> invalid src = 0.

template <int CTRL>
__device__ __forceinline__ u32 dpp32(u32 v) {
  return (u32)__builtin_amdgcn_update_dpp(0, (int)v, CTRL, 0xF, 0xF, true);
}

template <int CTRL>
__device__ __forceinline__ u32 dppumax(u32 v) {
  u32 s = dpp32<CTRL>(v);
  return (v > s) ? v : s;                        // v_max_u32
}

template <int CTRL>
__device__ __forceinline__ void dppmax64(u32& hi, u32& lo) {
  u32 h2 = dpp32<CTRL>(hi);
  u32 l2 = dpp32<CTRL>(lo);
  bool g = (h2 > hi) || (h2 == hi && l2 > lo);
  hi = g ? h2 : hi;
  lo = g ? l2 : lo;
}

// 16-lane butterfly -> ALL lanes hold the result (cross-wave finalize, wave0 only)
__device__ __forceinline__ u64 bfly16_max_u64(u64 key) {
  u32 lo = (u32)key, hi = (u32)(key >> 32);
  dppmax64<0xB1>(hi, lo); dppmax64<0x4E>(hi, lo);
  dppmax64<0x141>(hi, lo); dppmax64<0x140>(hi, lo);
  return ((u64)hi << 32) | lo;
}

// ---------------- prep kernels (massively parallel) ----------------

#define TT 32
__global__ void transpose_k(const float* __restrict__ in, float* __restrict__ out) {
  __shared__ float tile[TT][TT + 1];
  int x = blockIdx.x * TT + threadIdx.x;
  int y = blockIdx.y * TT + threadIdx.y;
  for (int j = 0; j < TT; j += 8) tile[threadIdx.y + j][threadIdx.x] = in[(u64)(y + j) * NW + x];
  __syncthreads();
  x = blockIdx.y * TT + threadIdx.x;
  y = blockIdx.x * TT + threadIdx.y;
  for (int j = 0; j < TT; j += 8) out[(u64)(y + j) * NW + x] = tile[threadIdx.x][threadIdx.y + j];
}

// Natural layout: gumb[t*NW + i] = gumbel for element i at step t.
__global__ void gumbel_k(float* __restrict__ gumb) {
  long long idx = (long long)blockIdx.x * blockDim.x + threadIdx.x;
  if (idx >= (long long)NSTEPS * NW) return;
  int t = (int)(idx >> 12);
  int i = (int)(idx & (NW - 1));
  u32 kt0, kt1, kc0, kc1, ba, bb;
  tf2x32(0u, 42u, 0u, (u32)t, &kt0, &kt1);
  tf2x32(kt0, kt1, 0u, 1u, &kc0, &kc1);
  tf2x32(kc0, kc1, 0u, (u32)i, &ba, &bb);
  float u = unif01(ba ^ bb);
  if (u == 0.0f) u = 1.17549435e-38f;
  float t1 = (float)log((double)u);
  float t2 = (float)log((double)(-t1));
  gumb[idx] = -t2;
}

__global__ void posu_k(int* __restrict__ posArr, float* __restrict__ uArr) {
  int t = blockIdx.x * blockDim.x + threadIdx.x;
  if (t >= NSTEPS) return;
  u32 kt0, kt1, kp0, kp1, ku0, ku1, k2a, k2b, ra, rb, ua, ub;
  tf2x32(0u, 42u, 0u, (u32)t, &kt0, &kt1);
  tf2x32(kt0, kt1, 0u, 0u, &kp0, &kp1);
  tf2x32(kt0, kt1, 0u, 2u, &ku0, &ku1);
  tf2x32(kp0, kp1, 0u, 1u, &k2a, &k2b);
  tf2x32(k2a, k2b, 0u, 0u, &ra, &rb);
  posArr[t] = (int)((ra ^ rb) & (u32)(NW - 1));
  tf2x32(ku0, ku1, 0u, 0u, &ua, &ub);
  uArr[t] = unif01(ua ^ ub);
}

// ---------------- main chain kernel ----------------

// proposed sample element at index idx (reads pre-commit s_perm; uses np/pos/tm)
#define SAMPLE_AT(idx)                                                        \
  ((idx) < np ? (int)s_perm[(idx) + ((idx) >= pos)]                           \
              : ((idx) == np ? tm                                             \
                             : (int)s_perm[((idx)-1) + (((idx)-1) >= pos)]))

__global__ __launch_bounds__(NTHREADS)
void mcmc_fast16(const float* __restrict__ bigram,
                 const float* __restrict__ bigT,
                 const float* __restrict__ gumb,
                 const int* __restrict__ posArr,
                 const float* __restrict__ uArr,
                 const float* __restrict__ startv,
                 const float* __restrict__ endv,
                 int* __restrict__ out) {
  __shared__ u16    s_perm[NW];       // 8 KB   (random-access readers)
  __shared__ float  s_rowT[NW];       // 16 KB  bigT[tm,:]  (split arrays: b32 gathers)
  __shared__ float  s_rowB[NW];       // 16 KB  bigram[tm,:]
  __shared__ float  s_pairw[NW];      // 16 KB  (random-access: splitv)
  __shared__ u64    s_redu[NWAVES];
  __shared__ float  s_stm, s_etm, s_lpos, s_brgS, s_vn1, s_vn2;
  __shared__ int    s_accs, s_tmA;

  const int tid = threadIdx.x;
  const int lane = tid & 63;
  const int wid = tid >> 6;
  const int j0 = tid * 4;             // first owned element

  // ---- init: identity perm; pairw; stage step-0 rows ----
  for (int i = tid; i < NW; i += NTHREADS) s_perm[i] = (u16)i;
  ushort4 pq = make_ushort4((u16)j0, (u16)(j0 + 1), (u16)(j0 + 2), (u16)(j0 + 3));
  float4 pwq;
  pwq.x = bigram[(u64)j0 * NW + (j0 + 1)];
  pwq.y = bigram[(u64)(j0 + 1) * NW + (j0 + 2)];
  pwq.z = bigram[(u64)(j0 + 2) * NW + (j0 + 3)];
  pwq.w = (j0 + 3 < NW - 1) ? bigram[(u64)(j0 + 3) * NW + (j0 + 4)] : 0.0f;
  ((float4*)s_pairw)[tid] = pwq;

  int pos = posArr[0];
  int pn1 = posArr[1];
  float u_cur = uArr[0];
  float un1 = uArr[1];
  int tm = pos;                        // identity perm: perm[pos] == pos
  {
    float4 rb4 = ((const float4*)(bigram + (u64)tm * NW))[tid];
    float4 rt4 = ((const float4*)(bigT + (u64)tm * NW))[tid];
    ((float4*)s_rowB)[tid] = rb4;
    ((float4*)s_rowT)[tid] = rt4;
  }
  if (tid == 0) { s_stm = startv[tm]; s_etm = endv[tm]; }

  // wave0-carried uniform chain state (garbage in other waves, never read there)
  float start_cur = startv[0];
  float end_cur = endv[NW - 1];

  float4 g4 = ((const float4*)gumb)[tid];
  __syncthreads();

  for (int t = 0; t < NSTEPS; ++t) {
    // ---- Phase A ----
    const float gg[4] = {g4.x, g4.y, g4.z, g4.w};
    // speculative reject-branch staging (pn1 already in a register)
    const int tmR = (int)s_perm[pn1];
    const float4 rbR = ((const float4*)(bigram + (u64)tmR * NW))[tid];
    const float4 rtR = ((const float4*)(bigT + (u64)tmR * NW))[tid];
    float stmR = 0.0f, etmR = 0.0f;
    if (tid == 0) { stmR = startv[tmR]; etmR = endv[tmR]; }
    // next-next step stream prefetch
    int pn2; float un2;
    {
      int tn = (t + 1 < NSTEPS) ? (t + 1) : (NSTEPS - 1);
      int tn2 = (t + 2 < NSTEPS) ? (t + 2) : (NSTEPS - 1);
      g4 = ((const float4*)(gumb + ((u64)tn << 12)))[tid];   // for step t+1
      pn2 = posArr[tn2];
      un2 = uArr[tn2];
    }
    // wave0 uniform prefetch of all pos-only accept inputs (consumed in Phase B)
    float stm_r = 0.0f, etm_r = 0.0f, remL = 0.0f, remR = 0.0f, brgv = 0.0f;
    float sv0m = 0.0f, ev1m = 0.0f;
    if (wid == 0) {
      stm_r = s_stm; etm_r = s_etm;
      int pl = (pos > 0) ? (int)s_perm[pos - 1] : 0;
      int pr = (pos < NW - 1) ? (int)s_perm[pos + 1] : 0;
      if (pos > 0)      remL = s_rowT[pl];                 // B[P[pos-1], tm]
      if (pos < NW - 1) remR = s_rowB[pr];                 // B[tm, P[pos+1]]
      if (pos > 0 && pos < NW - 1) brgv = bigram[(u64)pl * NW + pr];  // fresh bridge
      sv0m = startv[(int)s_perm[(0 >= pos) ? 1 : 0]];
      ev1m = endv[(int)s_perm[(NW - 2) + ((NW - 2) >= pos)]];
      if (lane == 0) s_brgS = brgv;
    }

    // perm block (registers) + cross-wave edges
    const int p0i = pq.x, p1i = pq.y, p2i = pq.z, p3i = pq.w;
    int pm1, pp4;
    {
      u32 lo = (u32)pq.x | ((u32)pq.y << 16);
      u32 hi = (u32)pq.z | ((u32)pq.w << 16);
      pm1 = (int)(dpp32<0x138>(hi) >> 16);                   // lane-1's p3 = perm[j0-1]
      pp4 = (int)(dpp32<0x130>(lo) & 0xFFFFu);               // lane+1's p0 = perm[j0+4]
      if (lane == 0)  pm1 = (tid > 0) ? (int)s_perm[j0 - 1] : 0;
      if (lane == 63) pp4 = (tid < NTHREADS - 1) ? (int)s_perm[j0 + 4] : 0;
    }
    // pairw cross-wave edge reads (values consumed lazily in Phase C on accept)
    float pwm1_e = 0.0f, pwp4_e = 0.0f;
    if (lane == 0 && tid > 0) pwm1_e = s_pairw[j0 - 1];
    if (lane == 63 && tid < NTHREADS - 1) pwp4_e = s_pairw[j0 + 4];

    // perm2 values for owned j (register selects)
    const int w0 = (j0     >= pos) ? p1i : p0i;
    const int w1 = (j0 + 1 >= pos) ? p2i : p1i;
    const int w2 = (j0 + 2 >= pos) ? p3i : p2i;
    const int w3 = (j0 + 3 >= pos) ? pp4 : p3i;
    const int wprev = ((j0 - 1) >= pos) ? p0i : pm1;         // perm2[j0-1]
    // split-array b32 gathers (random idx -> ~2-way bank aliasing, ~free)
    const float t0v = s_rowT[w0];
    const float t1v = s_rowT[w1];
    const float t2v = s_rowT[w2];
    const float t3v = s_rowT[w3];
    const float b0v = s_rowB[w0];
    const float b1v = s_rowB[w1];
    const float b2v = s_rowB[w2];
    const float b3v = s_rowB[w3];
    float tprev = __uint_as_float(dpp32<0x138>(__float_as_uint(t3v)));
    if (lane == 0 && tid > 0) tprev = s_rowT[wprev];
    // logits (bit-identical adds: T + B, same order as R13/R15)
    float li0 = tprev + b0v;
    float li1 = t0v + b1v;
    float li2 = t1v + b2v;
    float li3 = t2v + b3v;
    if (tid == 0)            li0 = s_stm + b0v;
    if (tid == NTHREADS - 1) li3 = s_etm + t2v;
    if ((pos >> 2) == tid) {
      int k = pos & 3;
      s_lpos = (k == 0) ? li0 : ((k == 1) ? li1 : ((k == 2) ? li2 : li3));
    }
    // argmax: local f32 first-wins -> fkey -> 6x DPP v_max_u32 -> ballot -> one write.
    // Lane order == index order (contiguous mapping), so lowest tied lane == min index:
    // exact tie semantics of the u64-key reduction.
    {
      float sv0_ = gg[0] + li0;
      float sv1_ = gg[1] + li1;
      float sv2_ = gg[2] + li2;
      float sv3_ = gg[3] + li3;
      float mx = sv0_; int ix = j0;
      if (sv1_ > mx) { mx = sv1_; ix = j0 + 1; }
      if (sv2_ > mx) { mx = sv2_; ix = j0 + 2; }
      if (sv3_ > mx) { mx = sv3_; ix = j0 + 3; }
      u32 kloc = fkey(mx);                       // never 0 for finite f32
      u32 kr = kloc;
      kr = dppumax<0x111>(kr); kr = dppumax<0x112>(kr);
      kr = dppumax<0x114>(kr); kr = dppumax<0x118>(kr);
      kr = dppumax<0x142>(kr); kr = dppumax<0x143>(kr);
      u32 kmax = (u32)__builtin_amdgcn_readlane((int)kr, 63);
      u64 mask = __ballot(kloc == kmax);
      int wl = (int)(__ffsll((long long)mask)) - 1;
      if (lane == wl) s_redu[wid] = ((u64)kmax << 32) | (u32)(NW - 1 - ix);
    }
    light_bar();                                                      // B1

    // ---- Phase B: wave0 ONLY (waves 1-15 go straight to B_mid) ----
    if (wid == 0) {
      u64 bb = bfly16_max_u64(s_redu[lane & 15]);
      const int np = NW - 1 - (int)(bb & 0xFFFFFFFFu);
      int ls_i = (np >= 1) ? ((np - 1) + ((np - 1) >= pos)) : 0;
      int rs_i = (np <= NW - 2) ? (np + (np >= pos)) : 0;
      const int l_s = (int)s_perm[ls_i];
      const int r_s = (int)s_perm[rs_i];
      const int tmA = SAMPLE_AT(pn1);
      float splitv = 0.0f;
      if (np > 0 && np < NW - 1) {
        int k_s = (np - 1) + ((np - 1) >= pos);
        splitv = (np == pos) ? brgv : s_pairw[k_s];          // O(1) LDS lookup
      }
      float vnpm1 = (np >= 1)      ? s_rowT[l_s] : 0.0f;
      float vnp   = (np <= NW - 2) ? s_rowB[r_s] : 0.0f;
      float sv0 = (np > 0) ? sv0m : stm_r;
      float ev1 = (np < NW - 1) ? ev1m : etm_r;
      float lposv = s_lpos;
      double delta = 0.0;
      if (pos > 0)                 delta -= (double)remL;
      if (pos < NW - 1)            delta -= (double)remR;
      if (pos > 0 && pos < NW - 1) delta += (double)brgv;
      if (np > 0)                  delta += (double)vnpm1;
      if (np < NW - 1)             delta += (double)vnp;
      if (np > 0 && np < NW - 1)   delta -= (double)splitv;
      delta += ((double)sv0 - (double)start_cur) + ((double)ev1 - (double)end_cur);
      float lnp = (np == 0) ? (stm_r + vnp)
                : ((np == NW - 1) ? (etm_r + vnpm1) : (vnpm1 + vnp));
      double ed = delta + ((double)lnp - (double)lposv);
      float a = fminf(1.0f, expf((float)ed));
      int acc = (a > u_cur) ? 1 : 0;
      if (lane == 0) { s_accs = acc; s_vn1 = vnpm1; s_vn2 = vnp; s_tmA = tmA; }
      if (acc) { start_cur = sv0; end_cur = ev1; }
    }
    light_bar();                                                      // B_mid

    // ---- Phase C: lazy accept work; reject path is ~free ----
    const int acc = s_accs;
    int tm_next = tmR;
    float4 rb = rbR, rt = rtR;
    ushort4 st = pq;
    if (acc) {
      tm_next = s_tmA;
      rb = ((const float4*)(bigram + (u64)tm_next * NW))[tid];
      rt = ((const float4*)(bigT + (u64)tm_next * NW))[tid];
      u64 bb = bfly16_max_u64(s_redu[lane & 15]);            // s_redu stable until B_end
      const int np = NW - 1 - (int)(bb & 0xFFFFFFFFu);
      // stash from registers
      st.x = (j0     < np) ? (u16)w0 : ((j0     == np) ? (u16)tm : (u16)wprev);
      st.y = (j0 + 1 < np) ? (u16)w1 : ((j0 + 1 == np) ? (u16)tm : (u16)w0);
      st.z = (j0 + 2 < np) ? (u16)w2 : ((j0 + 2 == np) ? (u16)tm : (u16)w1);
      st.w = (j0 + 3 < np) ? (u16)w3 : ((j0 + 3 == np) ? (u16)tm : (u16)w2);
      ((ushort4*)s_perm)[tid] = st;                          // 1 ds_write_b64
      // pairw maintenance (verified formulas; pwm1/pwp4 via DPP on registers)
      float pwm1 = __uint_as_float(dpp32<0x138>(__float_as_uint(pwq.w)));
      float pwp4 = __uint_as_float(dpp32<0x130>(__float_as_uint(pwq.x)));
      if (lane == 0)  pwm1 = pwm1_e;
      if (lane == 63) pwp4 = pwp4_e;
      const float brgAll = s_brgS;
      float nv0, nv1, nv2, nv3;
      {
        float vA0 = (j0     < pos - 1) ? pwq.x : pwq.y;
        float vB0 = (j0 - 1 < pos - 1) ? pwm1  : pwq.x;
        nv0 = (j0 < np) ? vA0 : vB0;
        int kk0 = (j0 < np) ? j0 : j0 - 1;
        if (kk0 == pos - 1) nv0 = brgAll;

        float vA1 = (j0 + 1 < pos - 1) ? pwq.y : pwq.z;
        float vB1 = (j0     < pos - 1) ? pwq.x : pwq.y;
        nv1 = (j0 + 1 < np) ? vA1 : vB1;
        int kk1 = (j0 + 1 < np) ? j0 + 1 : j0;
        if (kk1 == pos - 1) nv1 = brgAll;

        float vA2 = (j0 + 2 < pos - 1) ? pwq.z : pwq.w;
        float vB2 = (j0 + 1 < pos - 1) ? pwq.y : pwq.z;
        nv2 = (j0 + 2 < np) ? vA2 : vB2;
        int kk2 = (j0 + 2 < np) ? j0 + 2 : j0 + 1;
        if (kk2 == pos - 1) nv2 = brgAll;

        float vA3 = (j0 + 3 < pos - 1) ? pwq.w : pwp4;
        float vB3 = (j0 + 2 < pos - 1) ? pwq.z : pwq.w;
        nv3 = (j0 + 3 < np) ? vA3 : vB3;
        int kk3 = (j0 + 3 < np) ? j0 + 3 : j0 + 2;
        if (kk3 == pos - 1) nv3 = brgAll;
      }
      const float vn1 = s_vn1, vn2 = s_vn2;
      float o0 = (j0     == np - 1) ? vn1 : ((j0     == np) ? vn2 : nv0);
      float o1 = (j0 + 1 == np - 1) ? vn1 : ((j0 + 1 == np) ? vn2 : nv1);
      float o2 = (j0 + 2 == np - 1) ? vn1 : ((j0 + 2 == np) ? vn2 : nv2);
      float o3 = (j0 + 3 == np - 1) ? vn1 : ((j0 + 3 == np) ? vn2 : nv3);
      if (j0 + 3 >= NW - 1) o3 = 0.0f;                       // pairw[NW-1] stays 0
      pwq = make_float4(o0, o1, o2, o3);
      ((float4*)s_pairw)[tid] = pwq;                         // 1 ds_write_b128
      if (tid == 0) { s_stm = startv[tm_next]; s_etm = endv[tm_next]; }
    } else {
      if (tid == 0) { s_stm = stmR; s_etm = etmR; }
    }
    ((float4*)s_rowB)[tid] = rb;   // vmcnt wait (register dep) lands here
    ((float4*)s_rowT)[tid] = rt;
    pq = st;                            // post-commit perm block, carried in registers
    tm = tm_next;
    pos = pn1; u_cur = un1;
    pn1 = pn2; un1 = un2;

    // ---- emit thinned sample (pure register -> global; no LDS dependency) ----
    if ((t % 10) == 8) {
      int row = (t - 8) / 10;
      int4 o4;
      o4.x = (int)pq.x; o4.y = (int)pq.y; o4.z = (int)pq.z; o4.w = (int)pq.w;
      ((int4*)(out + (u64)row * NW))[tid] = o4;
    }
    light_bar();                                                      // B_end
  }
}

// ---------------- fallback (R2 kernel, verified) ----------------

__global__ __launch_bounds__(NTHREADS)
void mcmc_kernel(const float* __restrict__ bigram,
                 const float* __restrict__ startv,
                 const float* __restrict__ endv,
                 int* __restrict__ out) {
  __shared__ int    s_perm[NW];
  __shared__ float  s_logit[NW];
  __shared__ float  s_gath[NW];
  __shared__ float  s_redf[NWAVES];
  __shared__ u64    s_redu[NWAVES];
  __shared__ double s_redd[NWAVES];
  __shared__ float  s_m, s_Z, s_w;
  __shared__ int    s_pos, s_tm, s_np, s_acc;
  __shared__ u32    s_kcat0, s_kcat1, s_ku0, s_ku1;

  const int tid = threadIdx.x;
  const int lane = tid & 63;
  const int wid = tid >> 6;

  for (int i = tid; i < NW; i += NTHREADS) s_perm[i] = i;
  for (int j = tid; j < NW - 1; j += NTHREADS) s_gath[j] = bigram[(u64)j * NW + (j + 1)];
  __syncthreads();
  if (tid == 0) {
    float S = 0.0f;
    for (int j = 0; j < NW - 1; ++j) S += s_gath[j];
    S = S + startv[0];
    S = S + endv[NW - 1];
    s_w = S;
  }
  __syncthreads();

  for (int t = 0; t < NSTEPS; ++t) {
    if (tid == 0) {
      u32 kt0, kt1;
      tf2x32(0u, 42u, 0u, (u32)t, &kt0, &kt1);
      u32 kp0, kp1, kc0, kc1, ku0, ku1;
      tf2x32(kt0, kt1, 0u, 0u, &kp0, &kp1);
      tf2x32(kt0, kt1, 0u, 1u, &kc0, &kc1);
      tf2x32(kt0, kt1, 0u, 2u, &ku0, &ku1);
      u32 k2a, k2b, ra, rb;
      tf2x32(kp0, kp1, 0u, 1u, &k2a, &k2b);
      tf2x32(k2a, k2b, 0u, 0u, &ra, &rb);
      int pos = (int)((ra ^ rb) & (u32)(NW - 1));
      s_pos = pos;
      s_tm = s_perm[pos];
      s_kcat0 = kc0; s_kcat1 = kc1; s_ku0 = ku0; s_ku1 = ku1;
    }
    __syncthreads();
    const int pos = s_pos, tm = s_tm;

    float lmax = -3.402823466e+38f;
    for (int i = tid; i < NW; i += NTHREADS) {
      float li;
      if (i == 0) {
        int r = s_perm[(0 >= pos) ? 1 : 0];
        li = startv[tm] + bigram[(u64)tm * NW + r];
      } else if (i == NW - 1) {
        int l = s_perm[((NW - 2) >= pos) ? (NW - 1) : (NW - 2)];
        li = endv[tm] + bigram[(u64)l * NW + tm];
      } else {
        int l = s_perm[((i - 1) >= pos) ? i : (i - 1)];
        int r = s_perm[(i >= pos) ? (i + 1) : i];
        li = bigram[(u64)l * NW + tm] + bigram[(u64)tm * NW + r];
      }
      s_logit[i] = li;
      lmax = fmaxf(lmax, li);
    }
    for (int o = 32; o > 0; o >>= 1) lmax = fmaxf(lmax, __shfl_down(lmax, o, 64));
    if (lane == 0) s_redf[wid] = lmax;
    __syncthreads();
    if (tid == 0) {
      float m = s_redf[0];
      for (int w = 1; w < NWAVES; ++w) m = fmaxf(m, s_redf[w]);
      s_m = m;
    }
    __syncthreads();
    const float m = s_m;

    double zacc = 0.0;
    u64 best = 0;
    const u32 kc0 = s_kcat0, kc1 = s_kcat1;
    for (int i = tid; i < NW; i += NTHREADS) {
      float li = s_logit[i];
      float ex = (float)exp((double)(li - m));
      zacc += (double)ex;
      u32 ba, bb;
      tf2x32(kc0, kc1, 0u, (u32)i, &ba, &bb);
      float u = unif01(ba ^ bb);
      if (u == 0.0f) u = 1.17549435e-38f;
      float t1 = (float)log((double)u);
      float t2 = (float)log((double)(-t1));
      float g = -t2;
      float sv = g + li;
      u64 key = ((u64)fkey(sv) << 32) | (u32)(NW - 1 - i);
      if (key > best) best = key;
    }
    for (int o = 32; o > 0; o >>= 1) {
      u64 w = __shfl_down(best, o, 64);
      if (w > best) best = w;
      zacc += __shfl_down(zacc, o, 64);
    }
    if (lane == 0) { s_redu[wid] = best; s_redd[wid] = zacc; }
    __syncthreads();
    if (tid == 0) {
      u64 b = s_redu[0]; double z = s_redd[0];
      for (int w = 1; w < NWAVES; ++w) {
        if (s_redu[w] > b) b = s_redu[w];
        z += s_redd[w];
      }
      s_np = NW - 1 - (int)(b & 0xFFFFFFFFu);
      s_Z = (float)z;
    }
    __syncthreads();
    const int np = s_np;

    for (int j = tid; j < NW - 1; j += NTHREADS) {
      int a = (j < np) ? s_perm[j + (j >= pos)]
                       : ((j == np) ? tm : s_perm[(j - 1) + ((j - 1) >= pos)]);
      int j1 = j + 1;
      int b = (j1 < np) ? s_perm[j1 + (j1 >= pos)]
                        : ((j1 == np) ? tm : s_perm[(j1 - 1) + ((j1 - 1) >= pos)]);
      s_gath[j] = bigram[(u64)a * NW + b];
    }
    __syncthreads();

    if (tid == 0) {
      float S = 0.0f;
      for (int j = 0; j < NW - 1; ++j) S += s_gath[j];
      int s0 = (0 < np) ? s_perm[(0 >= pos) ? 1 : 0] : tm;
      int sl = ((NW - 1) == np) ? tm : s_perm[(NW - 2) + ((NW - 2) >= pos)];
      S = S + startv[s0];
      S = S + endv[sl];
      float dw = S - s_w;
      float e1 = (float)exp((double)dw);
      float en = (float)exp((double)(s_logit[np] - m));
      float eo = (float)exp((double)(s_logit[pos] - m));
      float pn = en / s_Z;
      float po = eo / s_Z;
      float acc = e1 * pn;
      acc = acc / po;
      acc = fminf(1.0f, acc);
      u32 ua, ub;
      tf2x32(s_ku0, s_ku1, 0u, 0u, &ua, &ub);
      float u = unif01(ua ^ ub);
      int accept = (acc > u) ? 1 : 0;
      s_acc = accept;
      if (accept) s_w = S;
    }
    __syncthreads();

    int stash[4];
    if (s_acc) {
      for (int k = 0; k < 4; ++k) {
        int i = tid + k * NTHREADS;
        stash[k] = (i < np) ? s_perm[i + (i >= pos)]
                            : ((i == np) ? tm : s_perm[(i - 1) + ((i - 1) >= pos)]);
      }
    }
    __syncthreads();
    if (s_acc) {
      for (int k = 0; k < 4; ++k) {
        int i = tid + k * NTHREADS;
        s_perm[i] = stash[k];
      }
    }
    __syncthreads();

    if (((t + 1) % 10) == 9) {
      int row = (t - 8) / 10;
      for (int i = tid; i < NW; i += NTHREADS) out[(u64)row * NW + i] = s_perm[i];
    }
    __syncthreads();
  }
}

extern "C" void kernel_launch(void* const* d_in, const int* in_sizes, int n_in,
                              void* d_out, int out_size, void* d_ws, size_t ws_size,
                              hipStream_t stream) {
  const float* bigram = (const float*)d_in[1];
  const float* startv = (const float*)d_in[2];
  const float* endv   = (const float*)d_in[3];
  int* out = (int*)d_out;

  const size_t needT = (size_t)NW * NW * sizeof(float);        // 64 MB
  const size_t needG = (size_t)NSTEPS * NW * sizeof(float);    // ~41.9 MB
  const size_t needP = (size_t)NSTEPS * (sizeof(int) + sizeof(float));

  if (ws_size >= needT + needG + needP) {
    float* bigT = (float*)d_ws;
    float* gumb = (float*)((char*)d_ws + needT);
    int* posArr = (int*)((char*)d_ws + needT + needG);
    float* uArr = (float*)((char*)d_ws + needT + needG + (size_t)NSTEPS * sizeof(int));
    hipLaunchKernelGGL(transpose_k, dim3(NW / TT, NW / TT), dim3(TT, 8), 0, stream,
                       bigram, bigT);
    long long ng = (long long)NSTEPS * NW;
    hipLaunchKernelGGL(gumbel_k, dim3((unsigned)((ng + 255) / 256)), dim3(256), 0, stream,
                       gumb);
    hipLaunchKernelGGL(posu_k, dim3((NSTEPS + 255) / 256), dim3(256), 0, stream,
                       posArr, uArr);
    hipLaunchKernelGGL(mcmc_fast16, dim3(1), dim3(NTHREADS), 0, stream,
                       bigram, bigT, gumb, posArr, uArr, startv, endv, out);
  } else {
    hipLaunchKernelGGL(mcmc_kernel, dim3(1), dim3(NTHREADS), 0, stream,
                       bigram, startv, endv, out);
  }
}

// Round 8
// 6387.530 us; speedup vs baseline: 1.1484x; 1.0170x over previous
//
#include <hip/hip_runtime.h>
#include <stdint.h>

// BetterMCMC R18: barrier-structure round (placement-only; numerics bit-identical R17).
//  1. Double-buffered rows[2]; speculative reject-rows staged in the B1->B_mid window
//     where waves 1-15 previously idled during wave0's serial decision. Staging
//     overlaps the decision for free; next-A reads rows[alt] (B_mid between).
//  2. Accept-only B_end: reject-path Phase C writes NOTHING to LDS (stm/etm promoted
//     to uniform registers; rows already staged; perm/pairw unchanged on reject) ->
//     third barrier only on accepts (~12%). Barriers/step 3 -> 2.12 avg.
// Race audit in analysis: every cross-phase LDS object has a barrier between
// writer and reader on every path.

#define NW 4096
#define NSTEPS 2559
#define NTHREADS 1024
#define NWAVES 16

typedef unsigned long long u64;
typedef uint32_t u32;
typedef unsigned short u16;

__device__ __forceinline__ u32 rotl32(u32 v, u32 r) { return (v << r) | (v >> (32u - r)); }

// Threefry-2x32, 20 rounds, exactly as jax/_src/prng.py threefry2x32.
__device__ __forceinline__ void tf2x32(u32 k0, u32 k1, u32 x0, u32 x1, u32* o0, u32* o1) {
  u32 ks2 = k0 ^ k1 ^ 0x1BD11BDAu;
  x0 += k0; x1 += k1;
#define TFR(r0, r1, r2, r3)                      \
  x0 += x1; x1 = rotl32(x1, r0); x1 ^= x0;       \
  x0 += x1; x1 = rotl32(x1, r1); x1 ^= x0;       \
  x0 += x1; x1 = rotl32(x1, r2); x1 ^= x0;       \
  x0 += x1; x1 = rotl32(x1, r3); x1 ^= x0;
  TFR(13, 15, 26, 6)  x0 += k1;  x1 += ks2 + 1u;
  TFR(17, 29, 16, 24) x0 += ks2; x1 += k0 + 2u;
  TFR(13, 15, 26, 6)  x0 += k0;  x1 += k1 + 3u;
  TFR(17, 29, 16, 24) x0 += k1;  x1 += ks2 + 4u;
  TFR(13, 15, 26, 6)  x0 += ks2; x1 += k0 + 5u;
#undef TFR
  *o0 = x0; *o1 = x1;
}

__device__ __forceinline__ float unif01(u32 bits) {
  return __uint_as_float((bits >> 9) | 0x3f800000u) - 1.0f;
}

__device__ __forceinline__ u32 fkey(float f) {
  u32 b = __float_as_uint(f);
  return b ^ ((b >> 31) ? 0xFFFFFFFFu : 0x80000000u);
}

// Light barrier: LDS-ordering only; global loads stay in flight (no vmcnt drain).
__device__ __forceinline__ void light_bar() {
  asm volatile("s_waitcnt lgkmcnt(0)" ::: "memory");
  __builtin_amdgcn_s_barrier();
  __builtin_amdgcn_sched_barrier(0);
  asm volatile("" ::: "memory");
}

// ---------------- DPP helpers (VALU, no LDS pipe) ----------------
// 0x138 wave_shr1: dest lane n <- lane n-1.  0x130 wave_shl1: dest lane n <- lane n+1.
// bound_ctrl=true -> invalid src = 0.

template <int CTRL>
__device__ __forceinline__ u32 dpp32(u32 v) {
  return (u32)__builtin_amdgcn_update_dpp(0, (int)v, CTRL, 0xF, 0xF, true);
}

template <int CTRL>
__device__ __forceinline__ u32 dppumax(u32 v) {
  u32 s = dpp32<CTRL>(v);
  return (v > s) ? v : s;                        // v_max_u32
}

template <int CTRL>
__device__ __forceinline__ void dppmax64(u32& hi, u32& lo) {
  u32 h2 = dpp32<CTRL>(hi);
  u32 l2 = dpp32<CTRL>(lo);
  bool g = (h2 > hi) || (h2 == hi && l2 > lo);
  hi = g ? h2 : hi;
  lo = g ? l2 : lo;
}

// 16-lane butterfly -> ALL lanes hold the result (cross-wave finalize)
__device__ __forceinline__ u64 bfly16_max_u64(u64 key) {
  u32 lo = (u32)key, hi = (u32)(key >> 32);
  dppmax64<0xB1>(hi, lo); dppmax64<0x4E>(hi, lo);
  dppmax64<0x141>(hi, lo); dppmax64<0x140>(hi, lo);
  return ((u64)hi << 32) | lo;
}

// ---------------- prep kernels (massively parallel) ----------------

#define TT 32
__global__ void transpose_k(const float* __restrict__ in, float* __restrict__ out) {
  __shared__ float tile[TT][TT + 1];
  int x = blockIdx.x * TT + threadIdx.x;
  int y = blockIdx.y * TT + threadIdx.y;
  for (int j = 0; j < TT; j += 8) tile[threadIdx.y + j][threadIdx.x] = in[(u64)(y + j) * NW + x];
  __syncthreads();
  x = blockIdx.y * TT + threadIdx.x;
  y = blockIdx.x * TT + threadIdx.y;
  for (int j = 0; j < TT; j += 8) out[(u64)(y + j) * NW + x] = tile[threadIdx.x][threadIdx.y + j];
}

// Natural layout: gumb[t*NW + i] = gumbel for element i at step t.
__global__ void gumbel_k(float* __restrict__ gumb) {
  long long idx = (long long)blockIdx.x * blockDim.x + threadIdx.x;
  if (idx >= (long long)NSTEPS * NW) return;
  int t = (int)(idx >> 12);
  int i = (int)(idx & (NW - 1));
  u32 kt0, kt1, kc0, kc1, ba, bb;
  tf2x32(0u, 42u, 0u, (u32)t, &kt0, &kt1);
  tf2x32(kt0, kt1, 0u, 1u, &kc0, &kc1);
  tf2x32(kc0, kc1, 0u, (u32)i, &ba, &bb);
  float u = unif01(ba ^ bb);
  if (u == 0.0f) u = 1.17549435e-38f;
  float t1 = (float)log((double)u);
  float t2 = (float)log((double)(-t1));
  gumb[idx] = -t2;
}

__global__ void posu_k(int* __restrict__ posArr, float* __restrict__ uArr) {
  int t = blockIdx.x * blockDim.x + threadIdx.x;
  if (t >= NSTEPS) return;
  u32 kt0, kt1, kp0, kp1, ku0, ku1, k2a, k2b, ra, rb, ua, ub;
  tf2x32(0u, 42u, 0u, (u32)t, &kt0, &kt1);
  tf2x32(kt0, kt1, 0u, 0u, &kp0, &kp1);
  tf2x32(kt0, kt1, 0u, 2u, &ku0, &ku1);
  tf2x32(kp0, kp1, 0u, 1u, &k2a, &k2b);
  tf2x32(k2a, k2b, 0u, 0u, &ra, &rb);
  posArr[t] = (int)((ra ^ rb) & (u32)(NW - 1));
  tf2x32(ku0, ku1, 0u, 0u, &ua, &ub);
  uArr[t] = unif01(ua ^ ub);
}

// ---------------- main chain kernel ----------------

// proposed sample element at index idx (reads pre-commit s_perm; uses np/pos/tm)
#define SAMPLE_AT(idx)                                                        \
  ((idx) < np ? (int)s_perm[(idx) + ((idx) >= pos)]                           \
              : ((idx) == np ? tm                                             \
                             : (int)s_perm[((idx)-1) + (((idx)-1) >= pos)]))

__global__ __launch_bounds__(NTHREADS)
void mcmc_fast17(const float* __restrict__ bigram,
                 const float* __restrict__ bigT,
                 const float* __restrict__ gumb,
                 const int* __restrict__ posArr,
                 const float* __restrict__ uArr,
                 const float* __restrict__ startv,
                 const float* __restrict__ endv,
                 int* __restrict__ out) {
  __shared__ u16    s_perm[NW];       // 8 KB
  __shared__ float  s_rowT[2][NW];    // 32 KB  bigT[tm,:]  double-buffered
  __shared__ float  s_rowB[2][NW];    // 32 KB  bigram[tm,:]
  __shared__ float  s_pairw[NW];      // 16 KB  (random-access: splitv)
  __shared__ u64    s_redu[NWAVES];
  __shared__ float  s_lpos, s_brgS, s_vn1, s_vn2;
  __shared__ int    s_accs, s_tmA;

  const int tid = threadIdx.x;
  const int lane = tid & 63;
  const int wid = tid >> 6;
  const int j0 = tid * 4;             // first owned element
  int cur = 0;                        // rows buffer selector (uniform)

  // ---- init: identity perm; pairw; stage step-0 rows into buf 0 ----
  for (int i = tid; i < NW; i += NTHREADS) s_perm[i] = (u16)i;
  ushort4 pq = make_ushort4((u16)j0, (u16)(j0 + 1), (u16)(j0 + 2), (u16)(j0 + 3));
  float4 pwq;
  pwq.x = bigram[(u64)j0 * NW + (j0 + 1)];
  pwq.y = bigram[(u64)(j0 + 1) * NW + (j0 + 2)];
  pwq.z = bigram[(u64)(j0 + 2) * NW + (j0 + 3)];
  pwq.w = (j0 + 3 < NW - 1) ? bigram[(u64)(j0 + 3) * NW + (j0 + 4)] : 0.0f;
  ((float4*)s_pairw)[tid] = pwq;

  int pos = posArr[0];
  int pn1 = posArr[1];
  float u_cur = uArr[0];
  float un1 = uArr[1];
  int tm = pos;                        // identity perm: perm[pos] == pos
  {
    float4 rb4 = ((const float4*)(bigram + (u64)tm * NW))[tid];
    float4 rt4 = ((const float4*)(bigT + (u64)tm * NW))[tid];
    ((float4*)s_rowB[0])[tid] = rb4;
    ((float4*)s_rowT[0])[tid] = rt4;
  }
  // uniform per-thread scalars (identical across all threads)
  float stm_cur = startv[tm];
  float etm_cur = endv[tm];
  // wave0-carried accept state (garbage outside wave0, never read there)
  float start_cur = startv[0];
  float end_cur = endv[NW - 1];

  float4 g4 = ((const float4*)gumb)[tid];
  __syncthreads();

  for (int t = 0; t < NSTEPS; ++t) {
    const float* rowT = s_rowT[cur];
    const float* rowB = s_rowB[cur];

    // ---- Phase A ----
    const float gg[4] = {g4.x, g4.y, g4.z, g4.w};
    // speculative reject-branch loads (consumed post-B1 as staging writes)
    const int tmR = (int)s_perm[pn1];
    const float4 rbR = ((const float4*)(bigram + (u64)tmR * NW))[tid];
    const float4 rtR = ((const float4*)(bigT + (u64)tmR * NW))[tid];
    const float stmR = startv[tmR];              // uniform broadcast loads
    const float etmR = endv[tmR];
    // next-next step stream prefetch
    int pn2; float un2;
    {
      int tn = (t + 1 < NSTEPS) ? (t + 1) : (NSTEPS - 1);
      int tn2 = (t + 2 < NSTEPS) ? (t + 2) : (NSTEPS - 1);
      g4 = ((const float4*)(gumb + ((u64)tn << 12)))[tid];   // for step t+1
      pn2 = posArr[tn2];
      un2 = uArr[tn2];
    }
    // wave0 uniform prefetch of pos-only accept inputs (consumed in Phase B)
    float remL = 0.0f, remR = 0.0f, brgv = 0.0f, sv0m = 0.0f, ev1m = 0.0f;
    if (wid == 0) {
      int pl = (pos > 0) ? (int)s_perm[pos - 1] : 0;
      int pr = (pos < NW - 1) ? (int)s_perm[pos + 1] : 0;
      if (pos > 0)      remL = rowT[pl];                   // B[P[pos-1], tm]
      if (pos < NW - 1) remR = rowB[pr];                   // B[tm, P[pos+1]]
      if (pos > 0 && pos < NW - 1) brgv = bigram[(u64)pl * NW + pr];  // fresh bridge
      sv0m = startv[(int)s_perm[(0 >= pos) ? 1 : 0]];
      ev1m = endv[(int)s_perm[(NW - 2) + ((NW - 2) >= pos)]];
      if (lane == 0) s_brgS = brgv;
    }

    // perm block (registers) + cross-wave edges
    const int p0i = pq.x, p1i = pq.y, p2i = pq.z, p3i = pq.w;
    int pm1, pp4;
    {
      u32 lo = (u32)pq.x | ((u32)pq.y << 16);
      u32 hi = (u32)pq.z | ((u32)pq.w << 16);
      pm1 = (int)(dpp32<0x138>(hi) >> 16);                   // lane-1's p3 = perm[j0-1]
      pp4 = (int)(dpp32<0x130>(lo) & 0xFFFFu);               // lane+1's p0 = perm[j0+4]
      if (lane == 0)  pm1 = (tid > 0) ? (int)s_perm[j0 - 1] : 0;
      if (lane == 63) pp4 = (tid < NTHREADS - 1) ? (int)s_perm[j0 + 4] : 0;
    }
    // pairw cross-wave edge reads (consumed lazily in Phase C on accept)
    float pwm1_e = 0.0f, pwp4_e = 0.0f;
    if (lane == 0 && tid > 0) pwm1_e = s_pairw[j0 - 1];
    if (lane == 63 && tid < NTHREADS - 1) pwp4_e = s_pairw[j0 + 4];

    // perm2 values for owned j (register selects)
    const int w0 = (j0     >= pos) ? p1i : p0i;
    const int w1 = (j0 + 1 >= pos) ? p2i : p1i;
    const int w2 = (j0 + 2 >= pos) ? p3i : p2i;
    const int w3 = (j0 + 3 >= pos) ? pp4 : p3i;
    const int wprev = ((j0 - 1) >= pos) ? p0i : pm1;         // perm2[j0-1]
    // split-array b32 gathers
    const float t0v = rowT[w0];
    const float t1v = rowT[w1];
    const float t2v = rowT[w2];
    const float t3v = rowT[w3];
    const float b0v = rowB[w0];
    const float b1v = rowB[w1];
    const float b2v = rowB[w2];
    const float b3v = rowB[w3];
    float tprev = __uint_as_float(dpp32<0x138>(__float_as_uint(t3v)));
    if (lane == 0 && tid > 0) tprev = rowT[wprev];
    // logits (bit-identical adds: T + B)
    float li0 = tprev + b0v;
    float li1 = t0v + b1v;
    float li2 = t1v + b2v;
    float li3 = t2v + b3v;
    if (tid == 0)            li0 = stm_cur + b0v;
    if (tid == NTHREADS - 1) li3 = etm_cur + t2v;
    if ((pos >> 2) == tid) {
      int k = pos & 3;
      s_lpos = (k == 0) ? li0 : ((k == 1) ? li1 : ((k == 2) ? li2 : li3));
    }
    // argmax: local f32 first-wins -> fkey -> DPP v_max_u32 -> ballot -> one write
    {
      float sv0_ = gg[0] + li0;
      float sv1_ = gg[1] + li1;
      float sv2_ = gg[2] + li2;
      float sv3_ = gg[3] + li3;
      float mx = sv0_; int ix = j0;
      if (sv1_ > mx) { mx = sv1_; ix = j0 + 1; }
      if (sv2_ > mx) { mx = sv2_; ix = j0 + 2; }
      if (sv3_ > mx) { mx = sv3_; ix = j0 + 3; }
      u32 kloc = fkey(mx);                       // never 0 for finite f32
      u32 kr = kloc;
      kr = dppumax<0x111>(kr); kr = dppumax<0x112>(kr);
      kr = dppumax<0x114>(kr); kr = dppumax<0x118>(kr);
      kr = dppumax<0x142>(kr); kr = dppumax<0x143>(kr);
      u32 kmax = (u32)__builtin_amdgcn_readlane((int)kr, 63);
      u64 mask = __ballot(kloc == kmax);
      int wl = (int)(__ffsll((long long)mask)) - 1;
      if (lane == wl) s_redu[wid] = ((u64)kmax << 32) | (u32)(NW - 1 - ix);
    }
    light_bar();                                                      // B1

    // ---- B1->B_mid window: all waves stage reject-rows into rows[alt];
    //      wave0 additionally runs the serial decision (overlapped). ----
    ((float4*)s_rowB[cur ^ 1])[tid] = rbR;       // vmcnt wait covered by Phase A
    ((float4*)s_rowT[cur ^ 1])[tid] = rtR;
    if (wid == 0) {
      u64 bb = bfly16_max_u64(s_redu[lane & 15]);
      const int np = NW - 1 - (int)(bb & 0xFFFFFFFFu);
      int ls_i = (np >= 1) ? ((np - 1) + ((np - 1) >= pos)) : 0;
      int rs_i = (np <= NW - 2) ? (np + (np >= pos)) : 0;
      const int l_s = (int)s_perm[ls_i];
      const int r_s = (int)s_perm[rs_i];
      const int tmA = SAMPLE_AT(pn1);
      float splitv = 0.0f;
      if (np > 0 && np < NW - 1) {
        int k_s = (np - 1) + ((np - 1) >= pos);
        splitv = (np == pos) ? brgv : s_pairw[k_s];          // O(1) LDS lookup
      }
      float vnpm1 = (np >= 1)      ? rowT[l_s] : 0.0f;
      float vnp   = (np <= NW - 2) ? rowB[r_s] : 0.0f;
      float sv0 = (np > 0) ? sv0m : stm_cur;
      float ev1 = (np < NW - 1) ? ev1m : etm_cur;
      float lposv = s_lpos;
      double delta = 0.0;
      if (pos > 0)                 delta -= (double)remL;
      if (pos < NW - 1)            delta -= (double)remR;
      if (pos > 0 && pos < NW - 1) delta += (double)brgv;
      if (np > 0)                  delta += (double)vnpm1;
      if (np < NW - 1)             delta += (double)vnp;
      if (np > 0 && np < NW - 1)   delta -= (double)splitv;
      delta += ((double)sv0 - (double)start_cur) + ((double)ev1 - (double)end_cur);
      float lnp = (np == 0) ? (stm_cur + vnp)
                : ((np == NW - 1) ? (etm_cur + vnpm1) : (vnpm1 + vnp));
      double ed = delta + ((double)lnp - (double)lposv);
      float a = fminf(1.0f, expf((float)ed));
      int acc = (a > u_cur) ? 1 : 0;
      if (lane == 0) { s_accs = acc; s_vn1 = vnpm1; s_vn2 = vnp; s_tmA = tmA; }
      if (acc) { start_cur = sv0; end_cur = ev1; }
    }
    light_bar();                                                      // B_mid

    // ---- Phase C: reject path writes NO LDS (no B_end); accept commits + B_end ----
    const int acc = s_accs;
    int tm_next = tmR;
    float stmN = stmR, etmN = etmR;
    ushort4 st = pq;
    if (acc) {
      tm_next = s_tmA;
      const float4 rbA = ((const float4*)(bigram + (u64)tm_next * NW))[tid];
      const float4 rtA = ((const float4*)(bigT + (u64)tm_next * NW))[tid];
      stmN = startv[tm_next];
      etmN = endv[tm_next];
      u64 bb = bfly16_max_u64(s_redu[lane & 15]);            // stable until next-A
      const int np = NW - 1 - (int)(bb & 0xFFFFFFFFu);
      // stash from registers -> perm commit
      st.x = (j0     < np) ? (u16)w0 : ((j0     == np) ? (u16)tm : (u16)wprev);
      st.y = (j0 + 1 < np) ? (u16)w1 : ((j0 + 1 == np) ? (u16)tm : (u16)w0);
      st.z = (j0 + 2 < np) ? (u16)w2 : ((j0 + 2 == np) ? (u16)tm : (u16)w1);
      st.w = (j0 + 3 < np) ? (u16)w3 : ((j0 + 3 == np) ? (u16)tm : (u16)w2);
      ((ushort4*)s_perm)[tid] = st;                          // 1 ds_write_b64
      // pairw maintenance (verified formulas)
      float pwm1 = __uint_as_float(dpp32<0x138>(__float_as_uint(pwq.w)));
      float pwp4 = __uint_as_float(dpp32<0x130>(__float_as_uint(pwq.x)));
      if (lane == 0)  pwm1 = pwm1_e;
      if (lane == 63) pwp4 = pwp4_e;
      const float brgAll = s_brgS;
      float nv0, nv1, nv2, nv3;
      {
        float vA0 = (j0     < pos - 1) ? pwq.x : pwq.y;
        float vB0 = (j0 - 1 < pos - 1) ? pwm1  : pwq.x;
        nv0 = (j0 < np) ? vA0 : vB0;
        int kk0 = (j0 < np) ? j0 : j0 - 1;
        if (kk0 == pos - 1) nv0 = brgAll;

        float vA1 = (j0 + 1 < pos - 1) ? pwq.y : pwq.z;
        float vB1 = (j0     < pos - 1) ? pwq.x : pwq.y;
        nv1 = (j0 + 1 < np) ? vA1 : vB1;
        int kk1 = (j0 + 1 < np) ? j0 + 1 : j0;
        if (kk1 == pos - 1) nv1 = brgAll;

        float vA2 = (j0 + 2 < pos - 1) ? pwq.z : pwq.w;
        float vB2 = (j0 + 1 < pos - 1) ? pwq.y : pwq.z;
        nv2 = (j0 + 2 < np) ? vA2 : vB2;
        int kk2 = (j0 + 2 < np) ? j0 + 2 : j0 + 1;
        if (kk2 == pos - 1) nv2 = brgAll;

        float vA3 = (j0 + 3 < pos - 1) ? pwq.w : pwp4;
        float vB3 = (j0 + 2 < pos - 1) ? pwq.z : pwq.w;
        nv3 = (j0 + 3 < np) ? vA3 : vB3;
        int kk3 = (j0 + 3 < np) ? j0 + 3 : j0 + 2;
        if (kk3 == pos - 1) nv3 = brgAll;
      }
      const float vn1 = s_vn1, vn2 = s_vn2;
      float o0 = (j0     == np - 1) ? vn1 : ((j0     == np) ? vn2 : nv0);
      float o1 = (j0 + 1 == np - 1) ? vn1 : ((j0 + 1 == np) ? vn2 : nv1);
      float o2 = (j0 + 2 == np - 1) ? vn1 : ((j0 + 2 == np) ? vn2 : nv2);
      float o3 = (j0 + 3 == np - 1) ? vn1 : ((j0 + 3 == np) ? vn2 : nv3);
      if (j0 + 3 >= NW - 1) o3 = 0.0f;                       // pairw[NW-1] stays 0
      pwq = make_float4(o0, o1, o2, o3);
      ((float4*)s_pairw)[tid] = pwq;                         // 1 ds_write_b128
      // correct the staged rows (overwrite rows[alt] with tmA rows)
      ((float4*)s_rowB[cur ^ 1])[tid] = rbA;
      ((float4*)s_rowT[cur ^ 1])[tid] = rtA;
    }
    cur ^= 1;
    pq = st;
    stm_cur = stmN; etm_cur = etmN;
    tm = tm_next;
    pos = pn1; u_cur = un1;
    pn1 = pn2; un1 = un2;
    if (acc) light_bar();                                    // B_end (accept only)

    // ---- emit thinned sample (registers -> global; no LDS dependency) ----
    if ((t % 10) == 8) {
      int row = (t - 8) / 10;
      int4 o4;
      o4.x = (int)pq.x; o4.y = (int)pq.y; o4.z = (int)pq.z; o4.w = (int)pq.w;
      ((int4*)(out + (u64)row * NW))[tid] = o4;
    }
  }
}

// ---------------- fallback (R2 kernel, verified) ----------------

__global__ __launch_bounds__(NTHREADS)
void mcmc_kernel(const float* __restrict__ bigram,
                 const float* __restrict__ startv,
                 const float* __restrict__ endv,
                 int* __restrict__ out) {
  __shared__ int    s_perm[NW];
  __shared__ float  s_logit[NW];
  __shared__ float  s_gath[NW];
  __shared__ float  s_redf[NWAVES];
  __shared__ u64    s_redu[NWAVES];
  __shared__ double s_redd[NWAVES];
  __shared__ float  s_m, s_Z, s_w;
  __shared__ int    s_pos, s_tm, s_np, s_acc;
  __shared__ u32    s_kcat0, s_kcat1, s_ku0, s_ku1;

  const int tid = threadIdx.x;
  const int lane = tid & 63;
  const int wid = tid >> 6;

  for (int i = tid; i < NW; i += NTHREADS) s_perm[i] = i;
  for (int j = tid; j < NW - 1; j += NTHREADS) s_gath[j] = bigram[(u64)j * NW + (j + 1)];
  __syncthreads();
  if (tid == 0) {
    float S = 0.0f;
    for (int j = 0; j < NW - 1; ++j) S += s_gath[j];
    S = S + startv[0];
    S = S + endv[NW - 1];
    s_w = S;
  }
  __syncthreads();

  for (int t = 0; t < NSTEPS; ++t) {
    if (tid == 0) {
      u32 kt0, kt1;
      tf2x32(0u, 42u, 0u, (u32)t, &kt0, &kt1);
      u32 kp0, kp1, kc0, kc1, ku0, ku1;
      tf2x32(kt0, kt1, 0u, 0u, &kp0, &kp1);
      tf2x32(kt0, kt1, 0u, 1u, &kc0, &kc1);
      tf2x32(kt0, kt1, 0u, 2u, &ku0, &ku1);
      u32 k2a, k2b, ra, rb;
      tf2x32(kp0, kp1, 0u, 1u, &k2a, &k2b);
      tf2x32(k2a, k2b, 0u, 0u, &ra, &rb);
      int pos = (int)((ra ^ rb) & (u32)(NW - 1));
      s_pos = pos;
      s_tm = s_perm[pos];
      s_kcat0 = kc0; s_kcat1 = kc1; s_ku0 = ku0; s_ku1 = ku1;
    }
    __syncthreads();
    const int pos = s_pos, tm = s_tm;

    float lmax = -3.402823466e+38f;
    for (int i = tid; i < NW; i += NTHREADS) {
      float li;
      if (i == 0) {
        int r = s_perm[(0 >= pos) ? 1 : 0];
        li = startv[tm] + bigram[(u64)tm * NW + r];
      } else if (i == NW - 1) {
        int l = s_perm[((NW - 2) >= pos) ? (NW - 1) : (NW - 2)];
        li = endv[tm] + bigram[(u64)l * NW + tm];
      } else {
        int l = s_perm[((i - 1) >= pos) ? i : (i - 1)];
        int r = s_perm[(i >= pos) ? (i + 1) : i];
        li = bigram[(u64)l * NW + tm] + bigram[(u64)tm * NW + r];
      }
      s_logit[i] = li;
      lmax = fmaxf(lmax, li);
    }
    for (int o = 32; o > 0; o >>= 1) lmax = fmaxf(lmax, __shfl_down(lmax, o, 64));
    if (lane == 0) s_redf[wid] = lmax;
    __syncthreads();
    if (tid == 0) {
      float m = s_redf[0];
      for (int w = 1; w < NWAVES; ++w) m = fmaxf(m, s_redf[w]);
      s_m = m;
    }
    __syncthreads();
    const float m = s_m;

    double zacc = 0.0;
    u64 best = 0;
    const u32 kc0 = s_kcat0, kc1 = s_kcat1;
    for (int i = tid; i < NW; i += NTHREADS) {
      float li = s_logit[i];
      float ex = (float)exp((double)(li - m));
      zacc += (double)ex;
      u32 ba, bb;
      tf2x32(kc0, kc1, 0u, (u32)i, &ba, &bb);
      float u = unif01(ba ^ bb);
      if (u == 0.0f) u = 1.17549435e-38f;
      float t1 = (float)log((double)u);
      float t2 = (float)log((double)(-t1));
      float g = -t2;
      float sv = g + li;
      u64 key = ((u64)fkey(sv) << 32) | (u32)(NW - 1 - i);
      if (key > best) best = key;
    }
    for (int o = 32; o > 0; o >>= 1) {
      u64 w = __shfl_down(best, o, 64);
      if (w > best) best = w;
      zacc += __shfl_down(zacc, o, 64);
    }
    if (lane == 0) { s_redu[wid] = best; s_redd[wid] = zacc; }
    __syncthreads();
    if (tid == 0) {
      u64 b = s_redu[0]; double z = s_redd[0];
      for (int w = 1; w < NWAVES; ++w) {
        if (s_redu[w] > b) b = s_redu[w];
        z += s_redd[w];
      }
      s_np = NW - 1 - (int)(b & 0xFFFFFFFFu);
      s_Z = (float)z;
    }
    __syncthreads();
    const int np = s_np;

    for (int j = tid; j < NW - 1; j += NTHREADS) {
      int a = (j < np) ? s_perm[j + (j >= pos)]
                       : ((j == np) ? tm : s_perm[(j - 1) + ((j - 1) >= pos)]);
      int j1 = j + 1;
      int b = (j1 < np) ? s_perm[j1 + (j1 >= pos)]
                        : ((j1 == np) ? tm : s_perm[(j1 - 1) + ((j1 - 1) >= pos)]);
      s_gath[j] = bigram[(u64)a * NW + b];
    }
    __syncthreads();

    if (tid == 0) {
      float S = 0.0f;
      for (int j = 0; j < NW - 1; ++j) S += s_gath[j];
      int s0 = (0 < np) ? s_perm[(0 >= pos) ? 1 : 0] : tm;
      int sl = ((NW - 1) == np) ? tm : s_perm[(NW - 2) + ((NW - 2) >= pos)];
      S = S + startv[s0];
      S = S + endv[sl];
      float dw = S - s_w;
      float e1 = (float)exp((double)dw);
      float en = (float)exp((double)(s_logit[np] - m));
      float eo = (float)exp((double)(s_logit[pos] - m));
      float pn = en / s_Z;
      float po = eo / s_Z;
      float acc = e1 * pn;
      acc = acc / po;
      acc = fminf(1.0f, acc);
      u32 ua, ub;
      tf2x32(s_ku0, s_ku1, 0u, 0u, &ua, &ub);
      float u = unif01(ua ^ ub);
      int accept = (acc > u) ? 1 : 0;
      s_acc = accept;
      if (accept) s_w = S;
    }
    __syncthreads();

    int stash[4];
    if (s_acc) {
      for (int k = 0; k < 4; ++k) {
        int i = tid + k * NTHREADS;
        stash[k] = (i < np) ? s_perm[i + (i >= pos)]
                            : ((i == np) ? tm : s_perm[(i - 1) + ((i - 1) >= pos)]);
      }
    }
    __syncthreads();
    if (s_acc) {
      for (int k = 0; k < 4; ++k) {
        int i = tid + k * NTHREADS;
        s_perm[i] = stash[k];
      }
    }
    __syncthreads();

    if (((t + 1) % 10) == 9) {
      int row = (t - 8) / 10;
      for (int i = tid; i < NW; i += NTHREADS) out[(u64)row * NW + i] = s_perm[i];
    }
    __syncthreads();
  }
}

extern "C" void kernel_launch(void* const* d_in, const int* in_sizes, int n_in,
                              void* d_out, int out_size, void* d_ws, size_t ws_size,
                              hipStream_t stream) {
  const float* bigram = (const float*)d_in[1];
  const float* startv = (const float*)d_in[2];
  const float* endv   = (const float*)d_in[3];
  int* out = (int*)d_out;

  const size_t needT = (size_t)NW * NW * sizeof(float);        // 64 MB
  const size_t needG = (size_t)NSTEPS * NW * sizeof(float);    // ~41.9 MB
  const size_t needP = (size_t)NSTEPS * (sizeof(int) + sizeof(float));

  if (ws_size >= needT + needG + needP) {
    float* bigT = (float*)d_ws;
    float* gumb = (float*)((char*)d_ws + needT);
    int* posArr = (int*)((char*)d_ws + needT + needG);
    float* uArr = (float*)((char*)d_ws + needT + needG + (size_t)NSTEPS * sizeof(int));
    hipLaunchKernelGGL(transpose_k, dim3(NW / TT, NW / TT), dim3(TT, 8), 0, stream,
                       bigram, bigT);
    long long ng = (long long)NSTEPS * NW;
    hipLaunchKernelGGL(gumbel_k, dim3((unsigned)((ng + 255) / 256)), dim3(256), 0, stream,
                       gumb);
    hipLaunchKernelGGL(posu_k, dim3((NSTEPS + 255) / 256), dim3(256), 0, stream,
                       posArr, uArr);
    hipLaunchKernelGGL(mcmc_fast17, dim3(1), dim3(NTHREADS), 0, stream,
                       bigram, bigT, gumb, posArr, uArr, startv, endv, out);
  } else {
    hipLaunchKernelGGL(mcmc_kernel, dim3(1), dim3(NTHREADS), 0, stream,
                       bigram, startv, endv, out);
  }
}

// Round 9
// 6196.761 us; speedup vs baseline: 1.1837x; 1.0308x over previous
//
#include <hip/hip_runtime.h>
#include <stdint.h>

// BetterMCMC R19: shorten wave0's serial decision (the ~470cy all-waves-wait segment).
//  1. s_wli[wid]: per-wave argmax winner also records its li. lnp = s_wli[np>>8]
//     (one broadcast read) -- the winner's li IS lnp, bitwise, in all cases.
//     Kills the 2-level perm->row indirection from the decision chain.
//  2. delta uses lnp (minus stm/etm for edge np) instead of vnpm1+vnp: ~1e-7
//     perturbation (np==pos residual ~1e-7 vs exact 0); chain survived 2e-4.
//  3. Exact vnpm1/vnp (accept-only pairw patch values) fetched in a PARALLEL chain.
//  4. s_brgS write moved Phase A -> Phase B: removes the pre-B1 vmcnt wait on the
//     L3 bridge load from wave0's Phase A (which gates all waves at B1).
// Decision ~470 -> ~270 cy. Everything else = R18 (verified).

#define NW 4096
#define NSTEPS 2559
#define NTHREADS 1024
#define NWAVES 16

typedef unsigned long long u64;
typedef uint32_t u32;
typedef unsigned short u16;

__device__ __forceinline__ u32 rotl32(u32 v, u32 r) { return (v << r) | (v >> (32u - r)); }

// Threefry-2x32, 20 rounds, exactly as jax/_src/prng.py threefry2x32.
__device__ __forceinline__ void tf2x32(u32 k0, u32 k1, u32 x0, u32 x1, u32* o0, u32* o1) {
  u32 ks2 = k0 ^ k1 ^ 0x1BD11BDAu;
  x0 += k0; x1 += k1;
#define TFR(r0, r1, r2, r3)                      \
  x0 += x1; x1 = rotl32(x1, r0); x1 ^= x0;       \
  x0 += x1; x1 = rotl32(x1, r1); x1 ^= x0;       \
  x0 += x1; x1 = rotl32(x1, r2); x1 ^= x0;       \
  x0 += x1; x1 = rotl32(x1, r3); x1 ^= x0;
  TFR(13, 15, 26, 6)  x0 += k1;  x1 += ks2 + 1u;
  TFR(17, 29, 16, 24) x0 += ks2; x1 += k0 + 2u;
  TFR(13, 15, 26, 6)  x0 += k0;  x1 += k1 + 3u;
  TFR(17, 29, 16, 24) x0 += k1;  x1 += ks2 + 4u;
  TFR(13, 15, 26, 6)  x0 += ks2; x1 += k0 + 5u;
#undef TFR
  *o0 = x0; *o1 = x1;
}

__device__ __forceinline__ float unif01(u32 bits) {
  return __uint_as_float((bits >> 9) | 0x3f800000u) - 1.0f;
}

__device__ __forceinline__ u32 fkey(float f) {
  u32 b = __float_as_uint(f);
  return b ^ ((b >> 31) ? 0xFFFFFFFFu : 0x80000000u);
}

// Light barrier: LDS-ordering only; global loads stay in flight (no vmcnt drain).
__device__ __forceinline__ void light_bar() {
  asm volatile("s_waitcnt lgkmcnt(0)" ::: "memory");
  __builtin_amdgcn_s_barrier();
  __builtin_amdgcn_sched_barrier(0);
  asm volatile("" ::: "memory");
}

// ---------------- DPP helpers (VALU, no LDS pipe) ----------------

template <int CTRL>
__device__ __forceinline__ u32 dpp32(u32 v) {
  return (u32)__builtin_amdgcn_update_dpp(0, (int)v, CTRL, 0xF, 0xF, true);
}

template <int CTRL>
__device__ __forceinline__ u32 dppumax(u32 v) {
  u32 s = dpp32<CTRL>(v);
  return (v > s) ? v : s;                        // v_max_u32
}

template <int CTRL>
__device__ __forceinline__ void dppmax64(u32& hi, u32& lo) {
  u32 h2 = dpp32<CTRL>(hi);
  u32 l2 = dpp32<CTRL>(lo);
  bool g = (h2 > hi) || (h2 == hi && l2 > lo);
  hi = g ? h2 : hi;
  lo = g ? l2 : lo;
}

// 16-lane butterfly -> ALL lanes hold the result (cross-wave finalize)
__device__ __forceinline__ u64 bfly16_max_u64(u64 key) {
  u32 lo = (u32)key, hi = (u32)(key >> 32);
  dppmax64<0xB1>(hi, lo); dppmax64<0x4E>(hi, lo);
  dppmax64<0x141>(hi, lo); dppmax64<0x140>(hi, lo);
  return ((u64)hi << 32) | lo;
}

// ---------------- prep kernels (massively parallel) ----------------

#define TT 32
__global__ void transpose_k(const float* __restrict__ in, float* __restrict__ out) {
  __shared__ float tile[TT][TT + 1];
  int x = blockIdx.x * TT + threadIdx.x;
  int y = blockIdx.y * TT + threadIdx.y;
  for (int j = 0; j < TT; j += 8) tile[threadIdx.y + j][threadIdx.x] = in[(u64)(y + j) * NW + x];
  __syncthreads();
  x = blockIdx.y * TT + threadIdx.x;
  y = blockIdx.x * TT + threadIdx.y;
  for (int j = 0; j < TT; j += 8) out[(u64)(y + j) * NW + x] = tile[threadIdx.x][threadIdx.y + j];
}

// Natural layout: gumb[t*NW + i] = gumbel for element i at step t.
__global__ void gumbel_k(float* __restrict__ gumb) {
  long long idx = (long long)blockIdx.x * blockDim.x + threadIdx.x;
  if (idx >= (long long)NSTEPS * NW) return;
  int t = (int)(idx >> 12);
  int i = (int)(idx & (NW - 1));
  u32 kt0, kt1, kc0, kc1, ba, bb;
  tf2x32(0u, 42u, 0u, (u32)t, &kt0, &kt1);
  tf2x32(kt0, kt1, 0u, 1u, &kc0, &kc1);
  tf2x32(kc0, kc1, 0u, (u32)i, &ba, &bb);
  float u = unif01(ba ^ bb);
  if (u == 0.0f) u = 1.17549435e-38f;
  float t1 = (float)log((double)u);
  float t2 = (float)log((double)(-t1));
  gumb[idx] = -t2;
}

__global__ void posu_k(int* __restrict__ posArr, float* __restrict__ uArr) {
  int t = blockIdx.x * blockDim.x + threadIdx.x;
  if (t >= NSTEPS) return;
  u32 kt0, kt1, kp0, kp1, ku0, ku1, k2a, k2b, ra, rb, ua, ub;
  tf2x32(0u, 42u, 0u, (u32)t, &kt0, &kt1);
  tf2x32(kt0, kt1, 0u, 0u, &kp0, &kp1);
  tf2x32(kt0, kt1, 0u, 2u, &ku0, &ku1);
  tf2x32(kp0, kp1, 0u, 1u, &k2a, &k2b);
  tf2x32(k2a, k2b, 0u, 0u, &ra, &rb);
  posArr[t] = (int)((ra ^ rb) & (u32)(NW - 1));
  tf2x32(ku0, ku1, 0u, 0u, &ua, &ub);
  uArr[t] = unif01(ua ^ ub);
}

// ---------------- main chain kernel ----------------

// proposed sample element at index idx (reads pre-commit s_perm; uses np/pos/tm)
#define SAMPLE_AT(idx)                                                        \
  ((idx) < np ? (int)s_perm[(idx) + ((idx) >= pos)]                           \
              : ((idx) == np ? tm                                             \
                             : (int)s_perm[((idx)-1) + (((idx)-1) >= pos)]))

__global__ __launch_bounds__(NTHREADS)
void mcmc_fast18(const float* __restrict__ bigram,
                 const float* __restrict__ bigT,
                 const float* __restrict__ gumb,
                 const int* __restrict__ posArr,
                 const float* __restrict__ uArr,
                 const float* __restrict__ startv,
                 const float* __restrict__ endv,
                 int* __restrict__ out) {
  __shared__ u16    s_perm[NW];       // 8 KB
  __shared__ float  s_rowT[2][NW];    // 32 KB  bigT[tm,:]  double-buffered
  __shared__ float  s_rowB[2][NW];    // 32 KB  bigram[tm,:]
  __shared__ float  s_pairw[NW];      // 16 KB  (random-access: splitv)
  __shared__ u64    s_redu[NWAVES];
  __shared__ float  s_wli[NWAVES];    // per-wave winner's li (lnp source)
  __shared__ float  s_lpos, s_brgS, s_vn1, s_vn2;
  __shared__ int    s_accs, s_tmA;

  const int tid = threadIdx.x;
  const int lane = tid & 63;
  const int wid = tid >> 6;
  const int j0 = tid * 4;             // first owned element
  int cur = 0;                        // rows buffer selector (uniform)

  // ---- init: identity perm; pairw; stage step-0 rows into buf 0 ----
  for (int i = tid; i < NW; i += NTHREADS) s_perm[i] = (u16)i;
  ushort4 pq = make_ushort4((u16)j0, (u16)(j0 + 1), (u16)(j0 + 2), (u16)(j0 + 3));
  float4 pwq;
  pwq.x = bigram[(u64)j0 * NW + (j0 + 1)];
  pwq.y = bigram[(u64)(j0 + 1) * NW + (j0 + 2)];
  pwq.z = bigram[(u64)(j0 + 2) * NW + (j0 + 3)];
  pwq.w = (j0 + 3 < NW - 1) ? bigram[(u64)(j0 + 3) * NW + (j0 + 4)] : 0.0f;
  ((float4*)s_pairw)[tid] = pwq;

  int pos = posArr[0];
  int pn1 = posArr[1];
  float u_cur = uArr[0];
  float un1 = uArr[1];
  int tm = pos;                        // identity perm: perm[pos] == pos
  {
    float4 rb4 = ((const float4*)(bigram + (u64)tm * NW))[tid];
    float4 rt4 = ((const float4*)(bigT + (u64)tm * NW))[tid];
    ((float4*)s_rowB[0])[tid] = rb4;
    ((float4*)s_rowT[0])[tid] = rt4;
  }
  // uniform per-thread scalars (identical across all threads)
  float stm_cur = startv[tm];
  float etm_cur = endv[tm];
  // wave0-carried accept state (garbage outside wave0, never read there)
  float start_cur = startv[0];
  float end_cur = endv[NW - 1];

  float4 g4 = ((const float4*)gumb)[tid];
  __syncthreads();

  for (int t = 0; t < NSTEPS; ++t) {
    const float* rowT = s_rowT[cur];
    const float* rowB = s_rowB[cur];

    // ---- Phase A ----
    const float gg[4] = {g4.x, g4.y, g4.z, g4.w};
    // speculative reject-branch loads (consumed post-B1 as staging writes)
    const int tmR = (int)s_perm[pn1];
    const float4 rbR = ((const float4*)(bigram + (u64)tmR * NW))[tid];
    const float4 rtR = ((const float4*)(bigT + (u64)tmR * NW))[tid];
    const float stmR = startv[tmR];              // uniform broadcast loads
    const float etmR = endv[tmR];
    // next-next step stream prefetch
    int pn2; float un2;
    {
      int tn = (t + 1 < NSTEPS) ? (t + 1) : (NSTEPS - 1);
      int tn2 = (t + 2 < NSTEPS) ? (t + 2) : (NSTEPS - 1);
      g4 = ((const float4*)(gumb + ((u64)tn << 12)))[tid];   // for step t+1
      pn2 = posArr[tn2];
      un2 = uArr[tn2];
    }
    // wave0 uniform prefetch of pos-only accept inputs (registers; consumed Phase B;
    // no LDS write here -> no pre-B1 vmcnt wait on the bridge load)
    float remL = 0.0f, remR = 0.0f, brgv = 0.0f, sv0m = 0.0f, ev1m = 0.0f;
    if (wid == 0) {
      int pl = (pos > 0) ? (int)s_perm[pos - 1] : 0;
      int pr = (pos < NW - 1) ? (int)s_perm[pos + 1] : 0;
      if (pos > 0)      remL = rowT[pl];                   // B[P[pos-1], tm]
      if (pos < NW - 1) remR = rowB[pr];                   // B[tm, P[pos+1]]
      if (pos > 0 && pos < NW - 1) brgv = bigram[(u64)pl * NW + pr];  // fresh bridge
      sv0m = startv[(int)s_perm[(0 >= pos) ? 1 : 0]];
      ev1m = endv[(int)s_perm[(NW - 2) + ((NW - 2) >= pos)]];
    }

    // perm block (registers) + cross-wave edges
    const int p0i = pq.x, p1i = pq.y, p2i = pq.z, p3i = pq.w;
    int pm1, pp4;
    {
      u32 lo = (u32)pq.x | ((u32)pq.y << 16);
      u32 hi = (u32)pq.z | ((u32)pq.w << 16);
      pm1 = (int)(dpp32<0x138>(hi) >> 16);                   // lane-1's p3 = perm[j0-1]
      pp4 = (int)(dpp32<0x130>(lo) & 0xFFFFu);               // lane+1's p0 = perm[j0+4]
      if (lane == 0)  pm1 = (tid > 0) ? (int)s_perm[j0 - 1] : 0;
      if (lane == 63) pp4 = (tid < NTHREADS - 1) ? (int)s_perm[j0 + 4] : 0;
    }
    // pairw cross-wave edge reads (consumed lazily in Phase C on accept)
    float pwm1_e = 0.0f, pwp4_e = 0.0f;
    if (lane == 0 && tid > 0) pwm1_e = s_pairw[j0 - 1];
    if (lane == 63 && tid < NTHREADS - 1) pwp4_e = s_pairw[j0 + 4];

    // perm2 values for owned j (register selects)
    const int w0 = (j0     >= pos) ? p1i : p0i;
    const int w1 = (j0 + 1 >= pos) ? p2i : p1i;
    const int w2 = (j0 + 2 >= pos) ? p3i : p2i;
    const int w3 = (j0 + 3 >= pos) ? pp4 : p3i;
    const int wprev = ((j0 - 1) >= pos) ? p0i : pm1;         // perm2[j0-1]
    // split-array b32 gathers
    const float t0v = rowT[w0];
    const float t1v = rowT[w1];
    const float t2v = rowT[w2];
    const float t3v = rowT[w3];
    const float b0v = rowB[w0];
    const float b1v = rowB[w1];
    const float b2v = rowB[w2];
    const float b3v = rowB[w3];
    float tprev = __uint_as_float(dpp32<0x138>(__float_as_uint(t3v)));
    if (lane == 0 && tid > 0) tprev = rowT[wprev];
    // logits (bit-identical adds: T + B)
    float li0 = tprev + b0v;
    float li1 = t0v + b1v;
    float li2 = t1v + b2v;
    float li3 = t2v + b3v;
    if (tid == 0)            li0 = stm_cur + b0v;
    if (tid == NTHREADS - 1) li3 = etm_cur + t2v;
    if ((pos >> 2) == tid) {
      int k = pos & 3;
      s_lpos = (k == 0) ? li0 : ((k == 1) ? li1 : ((k == 2) ? li2 : li3));
    }
    // argmax: local f32 first-wins -> fkey -> DPP v_max_u32 -> ballot -> one write.
    // Winning lane also records its winner's li (== lnp if this wave wins globally).
    {
      float sv0_ = gg[0] + li0;
      float sv1_ = gg[1] + li1;
      float sv2_ = gg[2] + li2;
      float sv3_ = gg[3] + li3;
      float mx = sv0_; int ix = j0; float lwin = li0;
      if (sv1_ > mx) { mx = sv1_; ix = j0 + 1; lwin = li1; }
      if (sv2_ > mx) { mx = sv2_; ix = j0 + 2; lwin = li2; }
      if (sv3_ > mx) { mx = sv3_; ix = j0 + 3; lwin = li3; }
      u32 kloc = fkey(mx);                       // never 0 for finite f32
      u32 kr = kloc;
      kr = dppumax<0x111>(kr); kr = dppumax<0x112>(kr);
      kr = dppumax<0x114>(kr); kr = dppumax<0x118>(kr);
      kr = dppumax<0x142>(kr); kr = dppumax<0x143>(kr);
      u32 kmax = (u32)__builtin_amdgcn_readlane((int)kr, 63);
      u64 mask = __ballot(kloc == kmax);
      int wl = (int)(__ffsll((long long)mask)) - 1;
      if (lane == wl) {
        s_redu[wid] = ((u64)kmax << 32) | (u32)(NW - 1 - ix);
        s_wli[wid] = lwin;
      }
    }
    light_bar();                                                      // B1

    // ---- B1->B_mid window: all waves stage reject-rows into rows[alt];
    //      wave0 additionally runs the (shortened) serial decision. ----
    ((float4*)s_rowB[cur ^ 1])[tid] = rbR;       // vmcnt wait covered by Phase A
    ((float4*)s_rowT[cur ^ 1])[tid] = rtR;
    if (wid == 0) {
      u64 bb = bfly16_max_u64(s_redu[lane & 15]);
      const int np = NW - 1 - (int)(bb & 0xFFFFFFFFu);
      // decision chain: lnp broadcast + splitv lookup (both 1-level, parallel)
      const float lnp = s_wli[np >> 8];
      float splitv = 0.0f;
      if (np > 0 && np < NW - 1) {
        int k_s = (np - 1) + ((np - 1) >= pos);
        splitv = (np == pos) ? brgv : s_pairw[k_s];
      }
      // parallel chain (accept-only consumers): exact vnpm1/vnp + tmA
      int ls_i = (np >= 1) ? ((np - 1) + ((np - 1) >= pos)) : 0;
      int rs_i = (np <= NW - 2) ? (np + (np >= pos)) : 0;
      const int l_s = (int)s_perm[ls_i];
      const int r_s = (int)s_perm[rs_i];
      const int tmA = SAMPLE_AT(pn1);
      float vnpm1 = (np >= 1)      ? rowT[l_s] : 0.0f;
      float vnp   = (np <= NW - 2) ? rowB[r_s] : 0.0f;
      float sv0 = (np > 0) ? sv0m : stm_cur;
      float ev1 = (np < NW - 1) ? ev1m : etm_cur;
      float lposv = s_lpos;
      const double dlnp = (double)lnp;
      double delta = 0.0;
      if (pos > 0)                 delta -= (double)remL;
      if (pos < NW - 1)            delta -= (double)remR;
      if (pos > 0 && pos < NW - 1) delta += (double)brgv;
      delta += dlnp;                              // = vnpm1+vnp (+stm/etm on edges)
      if (np == 0)           delta -= (double)stm_cur;
      else if (np == NW - 1) delta -= (double)etm_cur;
      if (np > 0 && np < NW - 1)   delta -= (double)splitv;
      delta += ((double)sv0 - (double)start_cur) + ((double)ev1 - (double)end_cur);
      double ed = delta + (dlnp - (double)lposv);
      float a = fminf(1.0f, expf((float)ed));
      int acc = (a > u_cur) ? 1 : 0;
      if (lane == 0) {
        s_accs = acc; s_vn1 = vnpm1; s_vn2 = vnp; s_tmA = tmA; s_brgS = brgv;
      }
      if (acc) { start_cur = sv0; end_cur = ev1; }
    }
    light_bar();                                                      // B_mid

    // ---- Phase C: reject path writes NO LDS (no B_end); accept commits + B_end ----
    const int acc = s_accs;
    int tm_next = tmR;
    float stmN = stmR, etmN = etmR;
    ushort4 st = pq;
    if (acc) {
      tm_next = s_tmA;
      const float4 rbA = ((const float4*)(bigram + (u64)tm_next * NW))[tid];
      const float4 rtA = ((const float4*)(bigT + (u64)tm_next * NW))[tid];
      stmN = startv[tm_next];
      etmN = endv[tm_next];
      u64 bb = bfly16_max_u64(s_redu[lane & 15]);            // stable until next-A
      const int np = NW - 1 - (int)(bb & 0xFFFFFFFFu);
      // stash from registers -> perm commit
      st.x = (j0     < np) ? (u16)w0 : ((j0     == np) ? (u16)tm : (u16)wprev);
      st.y = (j0 + 1 < np) ? (u16)w1 : ((j0 + 1 == np) ? (u16)tm : (u16)w0);
      st.z = (j0 + 2 < np) ? (u16)w2 : ((j0 + 2 == np) ? (u16)tm : (u16)w1);
      st.w = (j0 + 3 < np) ? (u16)w3 : ((j0 + 3 == np) ? (u16)tm : (u16)w2);
      ((ushort4*)s_perm)[tid] = st;                          // 1 ds_write_b64
      // pairw maintenance (verified formulas)
      float pwm1 = __uint_as_float(dpp32<0x138>(__float_as_uint(pwq.w)));
      float pwp4 = __uint_as_float(dpp32<0x130>(__float_as_uint(pwq.x)));
      if (lane == 0)  pwm1 = pwm1_e;
      if (lane == 63) pwp4 = pwp4_e;
      const float brgAll = s_brgS;
      float nv0, nv1, nv2, nv3;
      {
        float vA0 = (j0     < pos - 1) ? pwq.x : pwq.y;
        float vB0 = (j0 - 1 < pos - 1) ? pwm1  : pwq.x;
        nv0 = (j0 < np) ? vA0 : vB0;
        int kk0 = (j0 < np) ? j0 : j0 - 1;
        if (kk0 == pos - 1) nv0 = brgAll;

        float vA1 = (j0 + 1 < pos - 1) ? pwq.y : pwq.z;
        float vB1 = (j0     < pos - 1) ? pwq.x : pwq.y;
        nv1 = (j0 + 1 < np) ? vA1 : vB1;
        int kk1 = (j0 + 1 < np) ? j0 + 1 : j0;
        if (kk1 == pos - 1) nv1 = brgAll;

        float vA2 = (j0 + 2 < pos - 1) ? pwq.z : pwq.w;
        float vB2 = (j0 + 1 < pos - 1) ? pwq.y : pwq.z;
        nv2 = (j0 + 2 < np) ? vA2 : vB2;
        int kk2 = (j0 + 2 < np) ? j0 + 2 : j0 + 1;
        if (kk2 == pos - 1) nv2 = brgAll;

        float vA3 = (j0 + 3 < pos - 1) ? pwq.w : pwp4;
        float vB3 = (j0 + 2 < pos - 1) ? pwq.z : pwq.w;
        nv3 = (j0 + 3 < np) ? vA3 : vB3;
        int kk3 = (j0 + 3 < np) ? j0 + 3 : j0 + 2;
        if (kk3 == pos - 1) nv3 = brgAll;
      }
      const float vn1 = s_vn1, vn2 = s_vn2;
      float o0 = (j0     == np - 1) ? vn1 : ((j0     == np) ? vn2 : nv0);
      float o1 = (j0 + 1 == np - 1) ? vn1 : ((j0 + 1 == np) ? vn2 : nv1);
      float o2 = (j0 + 2 == np - 1) ? vn1 : ((j0 + 2 == np) ? vn2 : nv2);
      float o3 = (j0 + 3 == np - 1) ? vn1 : ((j0 + 3 == np) ? vn2 : nv3);
      if (j0 + 3 >= NW - 1) o3 = 0.0f;                       // pairw[NW-1] stays 0
      pwq = make_float4(o0, o1, o2, o3);
      ((float4*)s_pairw)[tid] = pwq;                         // 1 ds_write_b128
      // correct the staged rows (overwrite rows[alt] with tmA rows)
      ((float4*)s_rowB[cur ^ 1])[tid] = rbA;
      ((float4*)s_rowT[cur ^ 1])[tid] = rtA;
    }
    cur ^= 1;
    pq = st;
    stm_cur = stmN; etm_cur = etmN;
    tm = tm_next;
    pos = pn1; u_cur = un1;
    pn1 = pn2; un1 = un2;
    if (acc) light_bar();                                    // B_end (accept only)

    // ---- emit thinned sample (registers -> global; no LDS dependency) ----
    if ((t % 10) == 8) {
      int row = (t - 8) / 10;
      int4 o4;
      o4.x = (int)pq.x; o4.y = (int)pq.y; o4.z = (int)pq.z; o4.w = (int)pq.w;
      ((int4*)(out + (u64)row * NW))[tid] = o4;
    }
  }
}

// ---------------- fallback (R2 kernel, verified) ----------------

__global__ __launch_bounds__(NTHREADS)
void mcmc_kernel(const float* __restrict__ bigram,
                 const float* __restrict__ startv,
                 const float* __restrict__ endv,
                 int* __restrict__ out) {
  __shared__ int    s_perm[NW];
  __shared__ float  s_logit[NW];
  __shared__ float  s_gath[NW];
  __shared__ float  s_redf[NWAVES];
  __shared__ u64    s_redu[NWAVES];
  __shared__ double s_redd[NWAVES];
  __shared__ float  s_m, s_Z, s_w;
  __shared__ int    s_pos, s_tm, s_np, s_acc;
  __shared__ u32    s_kcat0, s_kcat1, s_ku0, s_ku1;

  const int tid = threadIdx.x;
  const int lane = tid & 63;
  const int wid = tid >> 6;

  for (int i = tid; i < NW; i += NTHREADS) s_perm[i] = i;
  for (int j = tid; j < NW - 1; j += NTHREADS) s_gath[j] = bigram[(u64)j * NW + (j + 1)];
  __syncthreads();
  if (tid == 0) {
    float S = 0.0f;
    for (int j = 0; j < NW - 1; ++j) S += s_gath[j];
    S = S + startv[0];
    S = S + endv[NW - 1];
    s_w = S;
  }
  __syncthreads();

  for (int t = 0; t < NSTEPS; ++t) {
    if (tid == 0) {
      u32 kt0, kt1;
      tf2x32(0u, 42u, 0u, (u32)t, &kt0, &kt1);
      u32 kp0, kp1, kc0, kc1, ku0, ku1;
      tf2x32(kt0, kt1, 0u, 0u, &kp0, &kp1);
      tf2x32(kt0, kt1, 0u, 1u, &kc0, &kc1);
      tf2x32(kt0, kt1, 0u, 2u, &ku0, &ku1);
      u32 k2a, k2b, ra, rb;
      tf2x32(kp0, kp1, 0u, 1u, &k2a, &k2b);
      tf2x32(k2a, k2b, 0u, 0u, &ra, &rb);
      int pos = (int)((ra ^ rb) & (u32)(NW - 1));
      s_pos = pos;
      s_tm = s_perm[pos];
      s_kcat0 = kc0; s_kcat1 = kc1; s_ku0 = ku0; s_ku1 = ku1;
    }
    __syncthreads();
    const int pos = s_pos, tm = s_tm;

    float lmax = -3.402823466e+38f;
    for (int i = tid; i < NW; i += NTHREADS) {
      float li;
      if (i == 0) {
        int r = s_perm[(0 >= pos) ? 1 : 0];
        li = startv[tm] + bigram[(u64)tm * NW + r];
      } else if (i == NW - 1) {
        int l = s_perm[((NW - 2) >= pos) ? (NW - 1) : (NW - 2)];
        li = endv[tm] + bigram[(u64)l * NW + tm];
      } else {
        int l = s_perm[((i - 1) >= pos) ? i : (i - 1)];
        int r = s_perm[(i >= pos) ? (i + 1) : i];
        li = bigram[(u64)l * NW + tm] + bigram[(u64)tm * NW + r];
      }
      s_logit[i] = li;
      lmax = fmaxf(lmax, li);
    }
    for (int o = 32; o > 0; o >>= 1) lmax = fmaxf(lmax, __shfl_down(lmax, o, 64));
    if (lane == 0) s_redf[wid] = lmax;
    __syncthreads();
    if (tid == 0) {
      float m = s_redf[0];
      for (int w = 1; w < NWAVES; ++w) m = fmaxf(m, s_redf[w]);
      s_m = m;
    }
    __syncthreads();
    const float m = s_m;

    double zacc = 0.0;
    u64 best = 0;
    const u32 kc0 = s_kcat0, kc1 = s_kcat1;
    for (int i = tid; i < NW; i += NTHREADS) {
      float li = s_logit[i];
      float ex = (float)exp((double)(li - m));
      zacc += (double)ex;
      u32 ba, bb;
      tf2x32(kc0, kc1, 0u, (u32)i, &ba, &bb);
      float u = unif01(ba ^ bb);
      if (u == 0.0f) u = 1.17549435e-38f;
      float t1 = (float)log((double)u);
      float t2 = (float)log((double)(-t1));
      float g = -t2;
      float sv = g + li;
      u64 key = ((u64)fkey(sv) << 32) | (u32)(NW - 1 - i);
      if (key > best) best = key;
    }
    for (int o = 32; o > 0; o >>= 1) {
      u64 w = __shfl_down(best, o, 64);
      if (w > best) best = w;
      zacc += __shfl_down(zacc, o, 64);
    }
    if (lane == 0) { s_redu[wid] = best; s_redd[wid] = zacc; }
    __syncthreads();
    if (tid == 0) {
      u64 b = s_redu[0]; double z = s_redd[0];
      for (int w = 1; w < NWAVES; ++w) {
        if (s_redu[w] > b) b = s_redu[w];
        z += s_redd[w];
      }
      s_np = NW - 1 - (int)(b & 0xFFFFFFFFu);
      s_Z = (float)z;
    }
    __syncthreads();
    const int np = s_np;

    for (int j = tid; j < NW - 1; j += NTHREADS) {
      int a = (j < np) ? s_perm[j + (j >= pos)]
                       : ((j == np) ? tm : s_perm[(j - 1) + ((j - 1) >= pos)]);
      int j1 = j + 1;
      int b = (j1 < np) ? s_perm[j1 + (j1 >= pos)]
                        : ((j1 == np) ? tm : s_perm[(j1 - 1) + ((j1 - 1) >= pos)]);
      s_gath[j] = bigram[(u64)a * NW + b];
    }
    __syncthreads();

    if (tid == 0) {
      float S = 0.0f;
      for (int j = 0; j < NW - 1; ++j) S += s_gath[j];
      int s0 = (0 < np) ? s_perm[(0 >= pos) ? 1 : 0] : tm;
      int sl = ((NW - 1) == np) ? tm : s_perm[(NW - 2) + ((NW - 2) >= pos)];
      S = S + startv[s0];
      S = S + endv[sl];
      float dw = S - s_w;
      float e1 = (float)exp((double)dw);
      float en = (float)exp((double)(s_logit[np] - m));
      float eo = (float)exp((double)(s_logit[pos] - m));
      float pn = en / s_Z;
      float po = eo / s_Z;
      float acc = e1 * pn;
      acc = acc / po;
      acc = fminf(1.0f, acc);
      u32 ua, ub;
      tf2x32(s_ku0, s_ku1, 0u, 0u, &ua, &ub);
      float u = unif01(ua ^ ub);
      int accept = (acc > u) ? 1 : 0;
      s_acc = accept;
      if (accept) s_w = S;
    }
    __syncthreads();

    int stash[4];
    if (s_acc) {
      for (int k = 0; k < 4; ++k) {
        int i = tid + k * NTHREADS;
        stash[k] = (i < np) ? s_perm[i + (i >= pos)]
                            : ((i == np) ? tm : s_perm[(i - 1) + ((i - 1) >= pos)]);
      }
    }
    __syncthreads();
    if (s_acc) {
      for (int k = 0; k < 4; ++k) {
        int i = tid + k * NTHREADS;
        s_perm[i] = stash[k];
      }
    }
    __syncthreads();

    if (((t + 1) % 10) == 9) {
      int row = (t - 8) / 10;
      for (int i = tid; i < NW; i += NTHREADS) out[(u64)row * NW + i] = s_perm[i];
    }
    __syncthreads();
  }
}

extern "C" void kernel_launch(void* const* d_in, const int* in_sizes, int n_in,
                              void* d_out, int out_size, void* d_ws, size_t ws_size,
                              hipStream_t stream) {
  const float* bigram = (const float*)d_in[1];
  const float* startv = (const float*)d_in[2];
  const float* endv   = (const float*)d_in[3];
  int* out = (int*)d_out;

  const size_t needT = (size_t)NW * NW * sizeof(float);        // 64 MB
  const size_t needG = (size_t)NSTEPS * NW * sizeof(float);    // ~41.9 MB
  const size_t needP = (size_t)NSTEPS * (sizeof(int) + sizeof(float));

  if (ws_size >= needT + needG + needP) {
    float* bigT = (float*)d_ws;
    float* gumb = (float*)((char*)d_ws + needT);
    int* posArr = (int*)((char*)d_ws + needT + needG);
    float* uArr = (float*)((char*)d_ws + needT + needG + (size_t)NSTEPS * sizeof(int));
    hipLaunchKernelGGL(transpose_k, dim3(NW / TT, NW / TT), dim3(TT, 8), 0, stream,
                       bigram, bigT);
    long long ng = (long long)NSTEPS * NW;
    hipLaunchKernelGGL(gumbel_k, dim3((unsigned)((ng + 255) / 256)), dim3(256), 0, stream,
                       gumb);
    hipLaunchKernelGGL(posu_k, dim3((NSTEPS + 255) / 256), dim3(256), 0, stream,
                       posArr, uArr);
    hipLaunchKernelGGL(mcmc_fast18, dim3(1), dim3(NTHREADS), 0, stream,
                       bigram, bigT, gumb, posArr, uArr, startv, endv, out);
  } else {
    hipLaunchKernelGGL(mcmc_kernel, dim3(1), dim3(NTHREADS), 0, stream,
                       bigram, startv, endv, out);
  }
}